// Round 13
// baseline (807.104 us; speedup 1.0000x reference)
//
#include <hip/hip_runtime.h>
#include <hip/hip_bf16.h>
#include <cstdint>
#include <cstddef>

#define N_S 4096
#define N_Kn 8192
#define HID 1024
#define SENT 1024
#define K3 3072

typedef __attribute__((ext_vector_type(4))) float f4;
typedef __attribute__((ext_vector_type(8))) short bf8;
typedef __attribute__((ext_vector_type(4))) short bf4;
typedef unsigned short u16;

__device__ __forceinline__ u16 f2bf(float x) {
    __hip_bfloat16 h = __float2bfloat16(x);   // HW RNE
    return __builtin_bit_cast(u16, h);
}
__device__ __forceinline__ float bf2f(u16 u) {
    union { unsigned int u; float f; } v; v.u = ((unsigned int)u) << 16;
    return v.f;
}

// async global->LDS, 16 bytes per lane; LDS dest = wave-uniform base + lane*16
__device__ __forceinline__ void gl16(const u16* g, u16* l) {
    __builtin_amdgcn_global_load_lds(
        (const __attribute__((address_space(1))) void*)g,
        (__attribute__((address_space(3))) void*)l, 16, 0, 0);
}

// bijective XCD swizzle (nwg % 8 == 0)
__device__ __forceinline__ int xcd_swz(int bid, int nwg) {
    const int cpx = nwg >> 3;
    return (bid & 7) * cpx + (bid >> 3);
}

#define BARR __builtin_amdgcn_s_barrier()
#define PRIO1 __builtin_amdgcn_s_setprio(1)
#define PRIO0 __builtin_amdgcn_s_setprio(0)
#define VM7  asm volatile("s_waitcnt vmcnt(7)" ::: "memory")
#define VM6  asm volatile("s_waitcnt vmcnt(6)" ::: "memory")
#define VM0  asm volatile("s_waitcnt vmcnt(0)" ::: "memory")

// ---------------------------------------------------------------------------
// Transposes
// ---------------------------------------------------------------------------
__global__ __launch_bounds__(256) void transpose_split_f32(
    const float* __restrict__ in, u16* __restrict__ hi, u16* __restrict__ lo,
    int R, int C)
{
    __shared__ float tile[32][33];
    const int bx = blockIdx.x * 32, by = blockIdx.y * 32;
    const int tx = threadIdx.x & 31, ty = threadIdx.x >> 5;
#pragma unroll
    for (int i = 0; i < 32; i += 8)
        tile[ty + i][tx] = in[(size_t)(by + ty + i) * C + bx + tx];
    __syncthreads();
#pragma unroll
    for (int i = 0; i < 32; i += 8) {
        const float v = tile[tx][ty + i];
        const u16 h = f2bf(v);
        const size_t o = (size_t)(bx + ty + i) * R + by + tx;
        hi[o] = h;
        lo[o] = f2bf(v - bf2f(h));
    }
}

__global__ __launch_bounds__(256) void transpose_f32_bf16(
    const float* __restrict__ in, u16* __restrict__ out, int R, int C)
{
    __shared__ float tile[32][33];
    const int bx = blockIdx.x * 32, by = blockIdx.y * 32;
    const int tx = threadIdx.x & 31, ty = threadIdx.x >> 5;
#pragma unroll
    for (int i = 0; i < 32; i += 8)
        tile[ty + i][tx] = in[(size_t)(by + ty + i) * C + bx + tx];
    __syncthreads();
#pragma unroll
    for (int i = 0; i < 32; i += 8)
        out[(size_t)(bx + ty + i) * R + by + tx] = f2bf(tile[tx][ty + i]);
}

// ---------------------------------------------------------------------------
// gemm8b: plain bf16 C = A @ B^T (GEMM6). BM=256, BN=192, BK=64, 512 thr
// (8 waves 4Mx2N), one-phase-ahead register prefetch so every MFMA cluster's
// ds_reads were issued >=1 phase earlier (LDS service overlaps MFMA),
// 3 barriers/tile, counted vmcnt(7), chunk-XOR swizzle. LDS 112 KiB.
//   ph0: read fb1(buf)            ; MMA Q(0,0)=fa0*fb0
//   ph1: read fa1(buf)            ; MMA Q(0,1)=fa0*fb1 ; BARR (B reads done)
//   ph2: stage t+2 B; read next fa0 (buf^1, landed); MMA Q(1,0)=fa1*fb0; BARR
//   ph3: stage t+2 A; read next fb0 (buf^1); MMA Q(1,1)=fa1*fb1; VM7; BARR
// Hazards: each stage lands after the barrier retiring that region's reads;
// buf^1 readability certified by previous tile's VM7 + boundary barrier.
// ---------------------------------------------------------------------------
#define GB_LDA(buf, mh, FA) \
  _Pragma("unroll") for (int mf_ = 0; mf_ < 2; ++mf_) \
  _Pragma("unroll") for (int kk_ = 0; kk_ < 2; ++kk_) \
    FA[mf_][kk_] = *(const bf8*)&sA[buf][(wm*64 + ((mh)*2+mf_)*16 + fr)*64 + (((kk_*4+kg) ^ (fr&7))<<3)];

#define GB_LDB(buf, nh, FB) \
  _Pragma("unroll") for (int nf_ = 0; nf_ < 3; ++nf_) \
  _Pragma("unroll") for (int kk_ = 0; kk_ < 2; ++kk_) \
    FB[nf_][kk_] = *(const bf8*)&sB[buf][(wn*96 + ((nh)*3+nf_)*16 + fr)*64 + (((kk_*4+kg) ^ (fr&7))<<3)];

#define GB_MMA(mh, nh, FA, FB) \
  _Pragma("unroll") for (int kk_ = 0; kk_ < 2; ++kk_) \
  _Pragma("unroll") for (int mf_ = 0; mf_ < 2; ++mf_) \
  _Pragma("unroll") for (int nf_ = 0; nf_ < 3; ++nf_) \
    acc[(mh)*2+mf_][(nh)*3+nf_] = __builtin_amdgcn_mfma_f32_16x16x32_bf16( \
        FA[mf_][kk_], FB[nf_][kk_], acc[(mh)*2+mf_][(nh)*3+nf_], 0, 0, 0);

__global__ __launch_bounds__(512, 2) void gemm8b(
    const u16* __restrict__ A, const u16* __restrict__ B,
    float* __restrict__ C, int N, int Kd, int gx)
{
    __shared__ u16 sA[2][256 * 64];
    __shared__ u16 sB[2][192 * 64];

    const int swz = xcd_swz(blockIdx.x, gridDim.x);
    const int bx = swz % gx, by = swz / gx;
    const long brow = (long)by * 256, bcol = (long)bx * 192;

    const int t = threadIdx.x;
    const int w = t >> 6, l = t & 63;
    const int fr = l & 15, kg = l >> 4;
    const int wm = w >> 1;           // 0..3 : wave row block (64 rows)
    const int wn = w & 1;            // 0..1 : wave col block (96 cols)

    const int srow = t >> 3;
    const int schk = ((t & 7) ^ (srow & 7)) << 3;
    const int sldb = w << 9;

    // hoisted staging pointers, advanced += 64 per K-tile
    const u16* pA0 = A + (brow +   0 + srow) * (long)Kd + schk;
    const u16* pA1 = A + (brow +  64 + srow) * (long)Kd + schk;
    const u16* pA2 = A + (brow + 128 + srow) * (long)Kd + schk;
    const u16* pA3 = A + (brow + 192 + srow) * (long)Kd + schk;
    const u16* pB0 = B + (bcol +   0 + srow) * (long)Kd + schk;
    const u16* pB1 = B + (bcol +  64 + srow) * (long)Kd + schk;
    const u16* pB2 = B + (bcol + 128 + srow) * (long)Kd + schk;

    auto stB3 = [&](int buf) {
        u16* base = &sB[buf][0];
        gl16(pB0, base + sldb);
        gl16(pB1, base + 4096 + sldb);
        gl16(pB2, base + 8192 + sldb);
    };
    auto stA4 = [&](int buf) {
        u16* base = &sA[buf][0];
        gl16(pA0, base + sldb);
        gl16(pA1, base + 4096 + sldb);
        gl16(pA2, base + 8192 + sldb);
        gl16(pA3, base + 12288 + sldb);
    };
    auto advance = [&]() {
        pA0 += 64; pA1 += 64; pA2 += 64; pA3 += 64;
        pB0 += 64; pB1 += 64; pB2 += 64;
    };

    f4 acc[4][6];
#pragma unroll
    for (int m = 0; m < 4; ++m)
#pragma unroll
        for (int n = 0; n < 6; ++n) acc[m][n] = (f4){0.f, 0.f, 0.f, 0.f};

    bf8 fa0[2][2], fa1[2][2], fb0[3][2], fb1[3][2];

    const int NK = Kd >> 6;

    // prologue: tile0 -> buf0, tile1 -> buf1; wait tile0; prime fa0/fb0
    stB3(0); stA4(0); advance();
    stB3(1); stA4(1); advance();
    VM7;
    BARR;
    GB_LDA(0, 0, fa0);
    GB_LDB(0, 0, fb0);

    for (int kt = 0; kt < NK; ++kt) {
        const int buf = kt & 1;
        const bool s2 = kt + 2 < NK;
        const bool more = kt + 1 < NK;

        // ph0: read fb1 (this tile); MMA Q(0,0)
        GB_LDB(buf, 1, fb1);
        PRIO1; GB_MMA(0, 0, fa0, fb0); PRIO0;

        // ph1: read fa1 (this tile); MMA Q(0,1); barrier retires B reads
        GB_LDA(buf, 1, fa1);
        PRIO1; GB_MMA(0, 1, fa0, fb1); PRIO0;
        BARR;

        // ph2: stage t+2 B (region retired); prefetch next tile's fa0 from
        // buf^1 (t+1 landed: prior tile's VM7 + boundary barrier); MMA Q(1,0)
        if (s2) { stB3(buf); }
        if (more) { GB_LDA(buf ^ 1, 0, fa0); }
        PRIO1; GB_MMA(1, 0, fa1, fb0); PRIO0;
        BARR;

        // ph3: stage t+2 A (region retired); prefetch next fb0; MMA Q(1,1);
        // counted wait; boundary barrier certifies t+1 landed for all waves
        if (s2) { stA4(buf); }
        if (more) { GB_LDB(buf ^ 1, 0, fb0); }
        PRIO1; GB_MMA(1, 1, fa1, fb1); PRIO0;
        if (s2) { VM7; } else { VM0; }
        BARR;
        advance();
    }

#pragma unroll
    for (int n = 0; n < 6; ++n) {
        const long c = bcol + wn * 96 + n * 16 + fr;
#pragma unroll
        for (int m = 0; m < 4; ++m) {
            const long r0 = brow + wm * 64 + m * 16 + kg * 4;
#pragma unroll
            for (int r = 0; r < 4; ++r)
                C[(r0 + r) * (long)N + c] = acc[m][n][r];
        }
    }
}

// ---------------------------------------------------------------------------
// gemm8s: split-bf16 C = A @ B^T (GEMM4), A,B pre-split hi/lo in workspace.
// BM=256, BN=128, BK=32, 512 thr (8 waves 4Mx2N), wave tile 64x64,
// 2 phases/tile: {16 ds_read; BARR; 24 MFMA} {stage t+2; VM6; BARR; 24 MFMA}.
// 3 MFMA products per frag pair (ah*bh + ah*bl + al*bh). LDS 96 KiB.
// Block order: XCD-paired rows (A panel L2-resident per XCD).
// ---------------------------------------------------------------------------
#define GS_LD(buf) \
  _Pragma("unroll") for (int m_ = 0; m_ < 4; ++m_) { \
    fah[m_] = *(const bf8*)&sAh[buf][(wm*64 + m_*16 + fr)*32 + kq]; \
    fal[m_] = *(const bf8*)&sAl[buf][(wm*64 + m_*16 + fr)*32 + kq]; } \
  _Pragma("unroll") for (int j_ = 0; j_ < 4; ++j_) { \
    fbh[j_] = *(const bf8*)&sBh[buf][(wn*64 + j_*16 + fr)*32 + kq]; \
    fbl[j_] = *(const bf8*)&sBl[buf][(wn*64 + j_*16 + fr)*32 + kq]; }

#define GS_MMA(nlo) \
  _Pragma("unroll") for (int m_ = 0; m_ < 4; ++m_) \
  _Pragma("unroll") for (int j_ = 0; j_ < 2; ++j_) { \
    const int n_ = (nlo)*2 + j_; \
    acc[m_][n_] = __builtin_amdgcn_mfma_f32_16x16x32_bf16(fah[m_], fbh[n_], acc[m_][n_], 0, 0, 0); \
    acc[m_][n_] = __builtin_amdgcn_mfma_f32_16x16x32_bf16(fah[m_], fbl[n_], acc[m_][n_], 0, 0, 0); \
    acc[m_][n_] = __builtin_amdgcn_mfma_f32_16x16x32_bf16(fal[m_], fbh[n_], acc[m_][n_], 0, 0, 0); }

__global__ __launch_bounds__(512, 2) void gemm8s(
    const u16* __restrict__ Ah, const u16* __restrict__ Al,
    const u16* __restrict__ Bh, const u16* __restrict__ Bl,
    float* __restrict__ C, int N, int Kd)
{
    __shared__ u16 sAh[2][8192], sAl[2][8192];
    __shared__ u16 sBh[2][4096], sBl[2][4096];

    const int bid = blockIdx.x;
    const int q = bid >> 3;
    const int by = (bid & 7) * 2 + (q & 1);   // 0..15 (XCD-paired rows)
    const int bx = q >> 1;                    // 0..63
    const long brow = (long)by * 256, bcol = (long)bx * 128;

    const int t = threadIdx.x;
    const int w = t >> 6, l = t & 63;
    const int fr = l & 15, kg = l >> 4;
    const int wm = w >> 1;                    // 0..3
    const int wn = w & 1;                     // 0..1
    const int kq = (kg ^ ((fr >> 1) & 3)) << 3;   // swizzled read chunk

    const int srow = t >> 2;                  // 0..127
    const int schk = ((t & 3) ^ ((t >> 3) & 3)) << 3;
    const int sldb = w << 9;

    const u16* pAh0 = Ah + (brow + srow) * (long)Kd + schk;
    const u16* pAh1 = Ah + (brow + 128 + srow) * (long)Kd + schk;
    const u16* pAl0 = Al + (brow + srow) * (long)Kd + schk;
    const u16* pAl1 = Al + (brow + 128 + srow) * (long)Kd + schk;
    const u16* pBh0 = Bh + (bcol + srow) * (long)Kd + schk;
    const u16* pBl0 = Bl + (bcol + srow) * (long)Kd + schk;

    auto stage6 = [&](int buf) {
        gl16(pBh0, &sBh[buf][sldb]);
        gl16(pBl0, &sBl[buf][sldb]);
        gl16(pAh0, &sAh[buf][sldb]);
        gl16(pAh1, &sAh[buf][4096 + sldb]);
        gl16(pAl0, &sAl[buf][sldb]);
        gl16(pAl1, &sAl[buf][4096 + sldb]);
    };
    auto advance = [&]() {
        pAh0 += 32; pAh1 += 32; pAl0 += 32; pAl1 += 32;
        pBh0 += 32; pBl0 += 32;
    };

    f4 acc[4][4];
#pragma unroll
    for (int m = 0; m < 4; ++m)
#pragma unroll
        for (int n = 0; n < 4; ++n) acc[m][n] = (f4){0.f, 0.f, 0.f, 0.f};

    bf8 fah[4], fal[4], fbh[4], fbl[4];

    const int NK = Kd >> 5;   // 32 tiles for K=1024

    stage6(0); advance();
    stage6(1); advance();
    VM6;
    BARR;

    for (int kt = 0; kt < NK; ++kt) {
        const int buf = kt & 1;
        const bool s2 = kt + 2 < NK;

        GS_LD(buf);
        BARR; PRIO1; GS_MMA(0); PRIO0;

        if (s2) { stage6(buf); VM6; } else { VM0; }
        BARR;
        PRIO1; GS_MMA(1); PRIO0;
        advance();
    }

#pragma unroll
    for (int n = 0; n < 4; ++n) {
        const long c = bcol + wn * 64 + n * 16 + fr;
#pragma unroll
        for (int m = 0; m < 4; ++m) {
            const long r0 = brow + wm * 64 + m * 16 + kg * 4;
#pragma unroll
            for (int r = 0; r < 4; ++r)
                C[(r0 + r) * (long)N + c] = acc[m][n][r];
        }
    }
}

// ---------------------------------------------------------------------------
// gemm_mfma: C[M][N] = A[M][K] @ B^T (+ bias); SPLIT/AF32/EPIS (GEMM2/3).
// Block order: XCD chunk -> 4x4 supertiles.
// ---------------------------------------------------------------------------
template <bool SPLIT, bool AF32, bool EPIS>
__global__ __launch_bounds__(256) void gemm_mfma(
    const void* __restrict__ Aany, const u16* __restrict__ Alo_,
    const u16* __restrict__ Bhi_, const u16* __restrict__ Blo_,
    float* __restrict__ Cf, u16* __restrict__ Chi, u16* __restrict__ Clo,
    const float* __restrict__ bias, int N, int Kd, int gx)
{
    constexpr int SA = AF32 ? 48 : 32;
    __shared__ u16 sAh[128 * SA];
    __shared__ u16 sAl[SPLIT ? 128 * SA : 8];
    __shared__ u16 sBh[128 * 32];
    __shared__ u16 sBl[SPLIT ? 128 * 32 : 8];

    const int swz = xcd_swz(blockIdx.x, gridDim.x);
    const int nst_x = gx >> 2;
    const int st = swz >> 4, off = swz & 15;
    const int bxi = (st % nst_x) * 4 + (off & 3);
    const int byi = (st / nst_x) * 4 + (off >> 2);

    const int t = threadIdx.x;
    const int w = t >> 6;
    const int l = t & 63;
    const long brow = (long)byi * 128;
    const long bcol = (long)bxi * 128;

    const int grow = l >> 2;
    const int gcol = ((l & 3) ^ ((l >> 3) & 3)) * 8;

    const int wr = (w >> 1) * 64;
    const int wc = (w & 1) * 64;
    const int fr = l & 15;
    const int kg = l >> 4;
    const int kq = (kg ^ ((fr >> 1) & 3)) * 8;

    f4 acc[4][4];
#pragma unroll
    for (int m = 0; m < 4; m++)
#pragma unroll
        for (int n = 0; n < 4; n++) acc[m][n] = (f4){0.f, 0.f, 0.f, 0.f};

    const int nkt = Kd >> 5;
    for (int kt = 0; kt < nkt; ++kt) {
        const int k0 = kt * 32;

#pragma unroll
        for (int i = 0; i < 2; ++i) {
            const long r = bcol + i * 64 + w * 16 + grow;
            const int lb = i * 2048 + w * 512;
            gl16(Bhi_ + r * Kd + k0 + gcol, sBh + lb);
            if constexpr (SPLIT) gl16(Blo_ + r * Kd + k0 + gcol, sBl + lb);
        }

        if constexpr (!AF32) {
            const u16* Ahi = (const u16*)Aany;
#pragma unroll
            for (int i = 0; i < 2; ++i) {
                const long r = brow + i * 64 + w * 16 + grow;
                const int lb = i * 2048 + w * 512;
                gl16(Ahi + r * Kd + k0 + gcol, sAh + lb);
                if constexpr (SPLIT) gl16(Alo_ + r * Kd + k0 + gcol, sAl + lb);
            }
        } else {
            const float* Af = (const float*)Aany;
            const int ar = w * 8 + (l >> 3);
            const int cF = (l & 7) * 4;
#pragma unroll
            for (int j = 0; j < 4; ++j) {
                const int r = j * 32 + ar;
                const f4 v = *(const f4*)(Af + (brow + r) * (long)Kd + k0 + cF);
                u16 h[4], lw[4];
#pragma unroll
                for (int q = 0; q < 4; ++q) {
                    h[q] = f2bf(v[q]);
                    if constexpr (SPLIT) lw[q] = f2bf(v[q] - bf2f(h[q]));
                }
                *(bf4*)&sAh[r * SA + cF] = *(bf4*)h;
                if constexpr (SPLIT) *(bf4*)&sAl[r * SA + cF] = *(bf4*)lw;
            }
        }
        __syncthreads();

        bf8 fah[4], fbh[4], fal[4], fbl[4];
#pragma unroll
        for (int m = 0; m < 4; ++m) {
            if constexpr (AF32) {
                fah[m] = *(bf8*)&sAh[(wr + m * 16 + fr) * SA + kg * 8];
                if constexpr (SPLIT) fal[m] = *(bf8*)&sAl[(wr + m * 16 + fr) * SA + kg * 8];
            } else {
                fah[m] = *(bf8*)&sAh[(wr + m * 16 + fr) * 32 + kq];
                if constexpr (SPLIT) fal[m] = *(bf8*)&sAl[(wr + m * 16 + fr) * 32 + kq];
            }
            fbh[m] = *(bf8*)&sBh[(wc + m * 16 + fr) * 32 + kq];
            if constexpr (SPLIT) fbl[m] = *(bf8*)&sBl[(wc + m * 16 + fr) * 32 + kq];
        }
#pragma unroll
        for (int m = 0; m < 4; ++m)
#pragma unroll
            for (int n = 0; n < 4; ++n) {
                acc[m][n] = __builtin_amdgcn_mfma_f32_16x16x32_bf16(fah[m], fbh[n], acc[m][n], 0, 0, 0);
                if constexpr (SPLIT) {
                    acc[m][n] = __builtin_amdgcn_mfma_f32_16x16x32_bf16(fah[m], fbl[n], acc[m][n], 0, 0, 0);
                    acc[m][n] = __builtin_amdgcn_mfma_f32_16x16x32_bf16(fal[m], fbh[n], acc[m][n], 0, 0, 0);
                }
            }
        __syncthreads();
    }

#pragma unroll
    for (int n = 0; n < 4; ++n) {
        const long c = bcol + wc + n * 16 + fr;
        float bv = 0.f;
        if constexpr (EPIS) bv = bias[c];
#pragma unroll
        for (int m = 0; m < 4; ++m) {
            const long r0 = brow + wr + m * 16 + kg * 4;
#pragma unroll
            for (int r = 0; r < 4; ++r) {
                const float v = acc[m][n][r] + bv;
                if constexpr (EPIS) {
                    const u16 h = f2bf(v);
                    Chi[(r0 + r) * (long)N + c] = h;
                    Clo[(r0 + r) * (long)N + c] = f2bf(v - bf2f(h));
                } else {
                    Cf[(r0 + r) * (long)N + c] = v;
                }
            }
        }
    }
}

// ---------------------------------------------------------------------------
// Column softmax over align [N_S rows][N_Kn cols] (softmax along axis 0)
// ---------------------------------------------------------------------------
#define RCHUNK 128

__global__ __launch_bounds__(256) void softmax_partial(
    const float* __restrict__ align, float* __restrict__ pm, float* __restrict__ ps)
{
    const int col = blockIdx.x * 256 + threadIdx.x;
    const int r0 = blockIdx.y * RCHUNK;
    float m = -3.4e38f;
    for (int r = 0; r < RCHUNK; r++)
        m = fmaxf(m, align[(size_t)(r0 + r) * N_Kn + col]);
    float s = 0.f;
    for (int r = 0; r < RCHUNK; r++)
        s += __expf(align[(size_t)(r0 + r) * N_Kn + col] - m);
    pm[(size_t)blockIdx.y * N_Kn + col] = m;
    ps[(size_t)blockIdx.y * N_Kn + col] = s;
}

__global__ __launch_bounds__(256) void softmax_combine(
    const float* __restrict__ pm, const float* __restrict__ ps,
    float* __restrict__ fm, float* __restrict__ fsinv)
{
    const int col = blockIdx.x * 256 + threadIdx.x;
    float m = -3.4e38f;
#pragma unroll
    for (int i = 0; i < 32; i++) m = fmaxf(m, pm[(size_t)i * N_Kn + col]);
    float s = 0.f;
#pragma unroll
    for (int i = 0; i < 32; i++)
        s += ps[(size_t)i * N_Kn + col] * __expf(pm[(size_t)i * N_Kn + col] - m);
    fm[col] = m;
    fsinv[col] = 1.f / s;
}

__global__ __launch_bounds__(256) void softmax_norm(
    float* __restrict__ align, u16* __restrict__ abf,
    const float* __restrict__ fm, const float* __restrict__ fsinv)
{
    const int col = blockIdx.x * 256 + threadIdx.x;
    const int r0 = blockIdx.y * RCHUNK;
    const float m = fm[col], si = fsinv[col];
    for (int r = 0; r < RCHUNK; r++) {
        const size_t idx = (size_t)(r0 + r) * N_Kn + col;
        const float v = __expf(align[idx] - m) * si;
        align[idx] = v;
        abf[idx] = f2bf(v);
    }
}

// ---------------------------------------------------------------------------
extern "C" void kernel_launch(void* const* d_in, const int* in_sizes, int n_in,
                              void* d_out, int out_size, void* d_ws, size_t ws_size,
                              hipStream_t stream)
{
    const float* sentences = (const float*)d_in[0];  // [4096][1024]
    const float* knowledge = (const float*)d_in[1];  // [8192][3072]
    const float* Ws = (const float*)d_in[2];         // [1024][1024]
    const float* bs = (const float*)d_in[3];         // [1024]
    const float* Wk = (const float*)d_in[4];         // [3072][1024]
    const float* bk = (const float*)d_in[5];         // [1024]

    float* out_fused = (float*)d_out;                        // [4096][3072]
    float* out_attn = (float*)d_out + (size_t)N_S * K3;      // [4096][8192]

    // workspace (~114 MB); first 64 MB reused as attn_bf16 after GEMM4
    char* w = (char*)d_ws;
    u16* attn_bf = (u16*)w;
    u16* WsT_hi = (u16*)w; w += (size_t)HID * SENT * 2;
    u16* WsT_lo = (u16*)w; w += (size_t)HID * SENT * 2;
    u16* WkT_hi = (u16*)w; w += (size_t)HID * K3 * 2;
    u16* WkT_lo = (u16*)w; w += (size_t)HID * K3 * 2;
    u16* S_hi   = (u16*)w; w += (size_t)N_S * HID * 2;
    u16* S_lo   = (u16*)w; w += (size_t)N_S * HID * 2;
    u16* K_hi   = (u16*)w; w += (size_t)N_Kn * HID * 2;
    u16* K_lo   = (u16*)w; w += (size_t)N_Kn * HID * 2;      // end = 64 MB
    u16* kT     = (u16*)w; w += (size_t)K3 * N_Kn * 2;
    float* pm   = (float*)w; w += (size_t)32 * N_Kn * 4;
    float* ps   = (float*)w; w += (size_t)32 * N_Kn * 4;
    float* fm   = (float*)w; w += (size_t)N_Kn * 4;
    float* fsv  = (float*)w; w += (size_t)N_Kn * 4;

    // 1. weight transposes (split) + knowledge^T (bf16)
    transpose_split_f32<<<dim3(HID / 32, SENT / 32), 256, 0, stream>>>(Ws, WsT_hi, WsT_lo, SENT, HID);
    transpose_split_f32<<<dim3(HID / 32, K3 / 32), 256, 0, stream>>>(Wk, WkT_hi, WkT_lo, K3, HID);
    transpose_f32_bf16<<<dim3(K3 / 32, N_Kn / 32), 256, 0, stream>>>(knowledge, kT, N_Kn, K3);

    // 2. S = sentences @ Ws + bs -> split bf16
    gemm_mfma<true, true, true><<<(HID / 128) * (N_S / 128), 256, 0, stream>>>(
        sentences, nullptr, WsT_hi, WsT_lo, nullptr, S_hi, S_lo, bs, HID, SENT, HID / 128);

    // 3. K = knowledge @ Wk + bk -> split bf16
    gemm_mfma<true, true, true><<<(HID / 128) * (N_Kn / 128), 256, 0, stream>>>(
        knowledge, nullptr, WkT_hi, WkT_lo, nullptr, K_hi, K_lo, bk, HID, K3, HID / 128);

    // 4. align = S @ K^T -> f32 into attentions slot (split, pipelined)
    gemm8s<<<(N_Kn / 128) * (N_S / 256), 512, 0, stream>>>(
        S_hi, S_lo, K_hi, K_lo, out_attn, N_Kn, HID);

    // 5. column softmax (axis 0), in place; emit bf16 attn into reused ws
    softmax_partial<<<dim3(N_Kn / 256, N_S / RCHUNK), 256, 0, stream>>>(out_attn, pm, ps);
    softmax_combine<<<dim3(N_Kn / 256), 256, 0, stream>>>(pm, ps, fm, fsv);
    softmax_norm<<<dim3(N_Kn / 256, N_S / RCHUNK), 256, 0, stream>>>(out_attn, attn_bf, fm, fsv);

    // 6. fused = attn_bf16 @ kT -> f32 (one-phase-ahead prefetch schedule)
    gemm8b<<<(K3 / 192) * (N_S / 256), 512, 0, stream>>>(
        attn_bf, kT, out_fused, K3, N_Kn, K3 / 192);
}

// Round 14
// 711.337 us; speedup vs baseline: 1.1346x; 1.1346x over previous
//
#include <hip/hip_runtime.h>
#include <hip/hip_bf16.h>
#include <cstdint>
#include <cstddef>

#define N_S 4096
#define N_Kn 8192
#define HID 1024
#define SENT 1024
#define K3 3072

typedef __attribute__((ext_vector_type(4))) float f4;
typedef __attribute__((ext_vector_type(8))) short bf8;
typedef __attribute__((ext_vector_type(4))) short bf4;
typedef unsigned short u16;

__device__ __forceinline__ u16 f2bf(float x) {
    __hip_bfloat16 h = __float2bfloat16(x);   // HW RNE
    return __builtin_bit_cast(u16, h);
}
__device__ __forceinline__ float bf2f(u16 u) {
    union { unsigned int u; float f; } v; v.u = ((unsigned int)u) << 16;
    return v.f;
}

// async global->LDS, 16 bytes per lane; LDS dest = wave-uniform base + lane*16
__device__ __forceinline__ void gl16(const u16* g, u16* l) {
    __builtin_amdgcn_global_load_lds(
        (const __attribute__((address_space(1))) void*)g,
        (__attribute__((address_space(3))) void*)l, 16, 0, 0);
}

// bijective XCD swizzle (nwg % 8 == 0)
__device__ __forceinline__ int xcd_swz(int bid, int nwg) {
    const int cpx = nwg >> 3;
    return (bid & 7) * cpx + (bid >> 3);
}

#define BARR __builtin_amdgcn_s_barrier()
#define PRIO1 __builtin_amdgcn_s_setprio(1)
#define PRIO0 __builtin_amdgcn_s_setprio(0)
#define VM7  asm volatile("s_waitcnt vmcnt(7)" ::: "memory")
#define VM6  asm volatile("s_waitcnt vmcnt(6)" ::: "memory")
#define VM0  asm volatile("s_waitcnt vmcnt(0)" ::: "memory")

// ---------------------------------------------------------------------------
// Transposes
// ---------------------------------------------------------------------------
__global__ __launch_bounds__(256) void transpose_split_f32(
    const float* __restrict__ in, u16* __restrict__ hi, u16* __restrict__ lo,
    int R, int C)
{
    __shared__ float tile[32][33];
    const int bx = blockIdx.x * 32, by = blockIdx.y * 32;
    const int tx = threadIdx.x & 31, ty = threadIdx.x >> 5;
#pragma unroll
    for (int i = 0; i < 32; i += 8)
        tile[ty + i][tx] = in[(size_t)(by + ty + i) * C + bx + tx];
    __syncthreads();
#pragma unroll
    for (int i = 0; i < 32; i += 8) {
        const float v = tile[tx][ty + i];
        const u16 h = f2bf(v);
        const size_t o = (size_t)(bx + ty + i) * R + by + tx;
        hi[o] = h;
        lo[o] = f2bf(v - bf2f(h));
    }
}

__global__ __launch_bounds__(256) void transpose_f32_bf16(
    const float* __restrict__ in, u16* __restrict__ out, int R, int C)
{
    __shared__ float tile[32][33];
    const int bx = blockIdx.x * 32, by = blockIdx.y * 32;
    const int tx = threadIdx.x & 31, ty = threadIdx.x >> 5;
#pragma unroll
    for (int i = 0; i < 32; i += 8)
        tile[ty + i][tx] = in[(size_t)(by + ty + i) * C + bx + tx];
    __syncthreads();
#pragma unroll
    for (int i = 0; i < 32; i += 8)
        out[(size_t)(bx + ty + i) * R + by + tx] = f2bf(tile[tx][ty + i]);
}

// ---------------------------------------------------------------------------
// gemm8b: plain bf16 C = A @ B^T (GEMM6). BM=256, BN=192, BK=64, 512 thr
// (8 waves 4Mx2N), single-barrier 4-phase schedule, counted vmcnt(7),
// chunk-XOR swizzle, hoisted staging pointers. LDS 112 KiB.
// (Round-10/11 schedule: reads(p); BARR; MMA(p) — each barrier region holds
//  MMA(p) of all waves + reads(p+1) of all waves. One-phase-ahead register
//  prefetch variant REGRESSED (r13: 297us vs 222us) — do not re-graft.)
// ---------------------------------------------------------------------------
#define GB_LDA(buf, mh) \
  _Pragma("unroll") for (int mf_ = 0; mf_ < 2; ++mf_) \
  _Pragma("unroll") for (int kk_ = 0; kk_ < 2; ++kk_) \
    fa[mf_][kk_] = *(const bf8*)&sA[buf][(wm*64 + ((mh)*2+mf_)*16 + fr)*64 + (((kk_*4+kg) ^ (fr&7))<<3)];

#define GB_LDB(buf, nh, FB) \
  _Pragma("unroll") for (int nf_ = 0; nf_ < 3; ++nf_) \
  _Pragma("unroll") for (int kk_ = 0; kk_ < 2; ++kk_) \
    FB[nf_][kk_] = *(const bf8*)&sB[buf][(wn*96 + ((nh)*3+nf_)*16 + fr)*64 + (((kk_*4+kg) ^ (fr&7))<<3)];

#define GB_MMA(mh, nh, FB) \
  _Pragma("unroll") for (int kk_ = 0; kk_ < 2; ++kk_) \
  _Pragma("unroll") for (int mf_ = 0; mf_ < 2; ++mf_) \
  _Pragma("unroll") for (int nf_ = 0; nf_ < 3; ++nf_) \
    acc[(mh)*2+mf_][(nh)*3+nf_] = __builtin_amdgcn_mfma_f32_16x16x32_bf16( \
        fa[mf_][kk_], FB[nf_][kk_], acc[(mh)*2+mf_][(nh)*3+nf_], 0, 0, 0);

__global__ __launch_bounds__(512, 2) void gemm8b(
    const u16* __restrict__ A, const u16* __restrict__ B,
    float* __restrict__ C, int N, int Kd, int gx)
{
    __shared__ u16 sA[2][256 * 64];
    __shared__ u16 sB[2][192 * 64];

    const int swz = xcd_swz(blockIdx.x, gridDim.x);
    const int bx = swz % gx, by = swz / gx;
    const long brow = (long)by * 256, bcol = (long)bx * 192;

    const int t = threadIdx.x;
    const int w = t >> 6, l = t & 63;
    const int fr = l & 15, kg = l >> 4;
    const int wm = w >> 1;           // 0..3 : wave row block (64 rows)
    const int wn = w & 1;            // 0..1 : wave col block (96 cols)

    const int srow = t >> 3;
    const int schk = ((t & 7) ^ (srow & 7)) << 3;
    const int sldb = w << 9;

    // hoisted staging pointers, advanced += 64 per K-tile
    const u16* pA0 = A + (brow +   0 + srow) * (long)Kd + schk;
    const u16* pA1 = A + (brow +  64 + srow) * (long)Kd + schk;
    const u16* pA2 = A + (brow + 128 + srow) * (long)Kd + schk;
    const u16* pA3 = A + (brow + 192 + srow) * (long)Kd + schk;
    const u16* pB0 = B + (bcol +   0 + srow) * (long)Kd + schk;
    const u16* pB1 = B + (bcol +  64 + srow) * (long)Kd + schk;
    const u16* pB2 = B + (bcol + 128 + srow) * (long)Kd + schk;

    auto stB3 = [&](int buf) {
        u16* base = &sB[buf][0];
        gl16(pB0, base + sldb);
        gl16(pB1, base + 4096 + sldb);
        gl16(pB2, base + 8192 + sldb);
    };
    auto stA4 = [&](int buf) {
        u16* base = &sA[buf][0];
        gl16(pA0, base + sldb);
        gl16(pA1, base + 4096 + sldb);
        gl16(pA2, base + 8192 + sldb);
        gl16(pA3, base + 12288 + sldb);
    };
    auto advance = [&]() {
        pA0 += 64; pA1 += 64; pA2 += 64; pA3 += 64;
        pB0 += 64; pB1 += 64; pB2 += 64;
    };

    f4 acc[4][6];
#pragma unroll
    for (int m = 0; m < 4; ++m)
#pragma unroll
        for (int n = 0; n < 6; ++n) acc[m][n] = (f4){0.f, 0.f, 0.f, 0.f};

    bf8 fa[2][2], fb0[3][2], fb1[3][2];

    const int NK = Kd >> 6;

    // prologue: tile0 -> buf0, tile1 -> buf1; wait tile0; pre-read fb0
    stB3(0); stA4(0); advance();
    stB3(1); stA4(1); advance();
    VM7;
    BARR;
    GB_LDB(0, 0, fb0);

    for (int kt = 0; kt < NK; ++kt) {
        const int buf = kt & 1;
        const bool s2 = kt + 2 < NK;
        const bool more = kt + 1 < NK;

        GB_LDA(buf, 0);
        BARR; PRIO1; GB_MMA(0, 0, fb0); PRIO0;

        GB_LDB(buf, 1, fb1);
        BARR; PRIO1; GB_MMA(0, 1, fb1); PRIO0;

        GB_LDA(buf, 1);
        if (s2) { stB3(buf); }
        BARR; PRIO1; GB_MMA(1, 0, fb0); PRIO0;

        if (s2) { stA4(buf); VM7; } else { VM0; }
        BARR;
        if (more) { GB_LDB(buf ^ 1, 0, fb0); }
        PRIO1; GB_MMA(1, 1, fb1); PRIO0;
        advance();
    }

#pragma unroll
    for (int n = 0; n < 6; ++n) {
        const long c = bcol + wn * 96 + n * 16 + fr;
#pragma unroll
        for (int m = 0; m < 4; ++m) {
            const long r0 = brow + wm * 64 + m * 16 + kg * 4;
#pragma unroll
            for (int r = 0; r < 4; ++r)
                C[(r0 + r) * (long)N + c] = acc[m][n][r];
        }
    }
}

// ---------------------------------------------------------------------------
// gemm8s: split-bf16 C = A @ B^T (GEMM4), A,B pre-split hi/lo in workspace.
// BM=256, BN=128, BK=32, 512 thr (8 waves 4Mx2N), wave tile 64x64,
// 2 phases/tile: {16 ds_read; BARR; 24 MFMA} {stage t+2; VM6; BARR; 24 MFMA}.
// 3 MFMA products per frag pair (ah*bh + ah*bl + al*bh). LDS 96 KiB.
// Block order: XCD-paired rows (A panel L2-resident per XCD).
// ---------------------------------------------------------------------------
#define GS_LD(buf) \
  _Pragma("unroll") for (int m_ = 0; m_ < 4; ++m_) { \
    fah[m_] = *(const bf8*)&sAh[buf][(wm*64 + m_*16 + fr)*32 + kq]; \
    fal[m_] = *(const bf8*)&sAl[buf][(wm*64 + m_*16 + fr)*32 + kq]; } \
  _Pragma("unroll") for (int j_ = 0; j_ < 4; ++j_) { \
    fbh[j_] = *(const bf8*)&sBh[buf][(wn*64 + j_*16 + fr)*32 + kq]; \
    fbl[j_] = *(const bf8*)&sBl[buf][(wn*64 + j_*16 + fr)*32 + kq]; }

#define GS_MMA(nlo) \
  _Pragma("unroll") for (int m_ = 0; m_ < 4; ++m_) \
  _Pragma("unroll") for (int j_ = 0; j_ < 2; ++j_) { \
    const int n_ = (nlo)*2 + j_; \
    acc[m_][n_] = __builtin_amdgcn_mfma_f32_16x16x32_bf16(fah[m_], fbh[n_], acc[m_][n_], 0, 0, 0); \
    acc[m_][n_] = __builtin_amdgcn_mfma_f32_16x16x32_bf16(fah[m_], fbl[n_], acc[m_][n_], 0, 0, 0); \
    acc[m_][n_] = __builtin_amdgcn_mfma_f32_16x16x32_bf16(fal[m_], fbh[n_], acc[m_][n_], 0, 0, 0); }

__global__ __launch_bounds__(512, 2) void gemm8s(
    const u16* __restrict__ Ah, const u16* __restrict__ Al,
    const u16* __restrict__ Bh, const u16* __restrict__ Bl,
    float* __restrict__ C, int N, int Kd)
{
    __shared__ u16 sAh[2][8192], sAl[2][8192];
    __shared__ u16 sBh[2][4096], sBl[2][4096];

    const int bid = blockIdx.x;
    const int q = bid >> 3;
    const int by = (bid & 7) * 2 + (q & 1);   // 0..15 (XCD-paired rows)
    const int bx = q >> 1;                    // 0..63
    const long brow = (long)by * 256, bcol = (long)bx * 128;

    const int t = threadIdx.x;
    const int w = t >> 6, l = t & 63;
    const int fr = l & 15, kg = l >> 4;
    const int wm = w >> 1;                    // 0..3
    const int wn = w & 1;                     // 0..1
    const int kq = (kg ^ ((fr >> 1) & 3)) << 3;   // swizzled read chunk

    const int srow = t >> 2;                  // 0..127
    const int schk = ((t & 3) ^ ((t >> 3) & 3)) << 3;
    const int sldb = w << 9;

    const u16* pAh0 = Ah + (brow + srow) * (long)Kd + schk;
    const u16* pAh1 = Ah + (brow + 128 + srow) * (long)Kd + schk;
    const u16* pAl0 = Al + (brow + srow) * (long)Kd + schk;
    const u16* pAl1 = Al + (brow + 128 + srow) * (long)Kd + schk;
    const u16* pBh0 = Bh + (bcol + srow) * (long)Kd + schk;
    const u16* pBl0 = Bl + (bcol + srow) * (long)Kd + schk;

    auto stage6 = [&](int buf) {
        gl16(pBh0, &sBh[buf][sldb]);
        gl16(pBl0, &sBl[buf][sldb]);
        gl16(pAh0, &sAh[buf][sldb]);
        gl16(pAh1, &sAh[buf][4096 + sldb]);
        gl16(pAl0, &sAl[buf][sldb]);
        gl16(pAl1, &sAl[buf][4096 + sldb]);
    };
    auto advance = [&]() {
        pAh0 += 32; pAh1 += 32; pAl0 += 32; pAl1 += 32;
        pBh0 += 32; pBl0 += 32;
    };

    f4 acc[4][4];
#pragma unroll
    for (int m = 0; m < 4; ++m)
#pragma unroll
        for (int n = 0; n < 4; ++n) acc[m][n] = (f4){0.f, 0.f, 0.f, 0.f};

    bf8 fah[4], fal[4], fbh[4], fbl[4];

    const int NK = Kd >> 5;   // 32 tiles for K=1024

    stage6(0); advance();
    stage6(1); advance();
    VM6;
    BARR;

    for (int kt = 0; kt < NK; ++kt) {
        const int buf = kt & 1;
        const bool s2 = kt + 2 < NK;

        GS_LD(buf);
        BARR; PRIO1; GS_MMA(0); PRIO0;

        if (s2) { stage6(buf); VM6; } else { VM0; }
        BARR;
        PRIO1; GS_MMA(1); PRIO0;
        advance();
    }

#pragma unroll
    for (int n = 0; n < 4; ++n) {
        const long c = bcol + wn * 64 + n * 16 + fr;
#pragma unroll
        for (int m = 0; m < 4; ++m) {
            const long r0 = brow + wm * 64 + m * 16 + kg * 4;
#pragma unroll
            for (int r = 0; r < 4; ++r)
                C[(r0 + r) * (long)N + c] = acc[m][n][r];
        }
    }
}

// ---------------------------------------------------------------------------
// gemm_mfma: C[M][N] = A[M][K] @ B^T (+ bias); SPLIT/AF32/EPIS (GEMM2/3).
// Block order: XCD chunk -> 4x4 supertiles.
// ---------------------------------------------------------------------------
template <bool SPLIT, bool AF32, bool EPIS>
__global__ __launch_bounds__(256) void gemm_mfma(
    const void* __restrict__ Aany, const u16* __restrict__ Alo_,
    const u16* __restrict__ Bhi_, const u16* __restrict__ Blo_,
    float* __restrict__ Cf, u16* __restrict__ Chi, u16* __restrict__ Clo,
    const float* __restrict__ bias, int N, int Kd, int gx)
{
    constexpr int SA = AF32 ? 48 : 32;
    __shared__ u16 sAh[128 * SA];
    __shared__ u16 sAl[SPLIT ? 128 * SA : 8];
    __shared__ u16 sBh[128 * 32];
    __shared__ u16 sBl[SPLIT ? 128 * 32 : 8];

    const int swz = xcd_swz(blockIdx.x, gridDim.x);
    const int nst_x = gx >> 2;
    const int st = swz >> 4, off = swz & 15;
    const int bxi = (st % nst_x) * 4 + (off & 3);
    const int byi = (st / nst_x) * 4 + (off >> 2);

    const int t = threadIdx.x;
    const int w = t >> 6;
    const int l = t & 63;
    const long brow = (long)byi * 128;
    const long bcol = (long)bxi * 128;

    const int grow = l >> 2;
    const int gcol = ((l & 3) ^ ((l >> 3) & 3)) * 8;

    const int wr = (w >> 1) * 64;
    const int wc = (w & 1) * 64;
    const int fr = l & 15;
    const int kg = l >> 4;
    const int kq = (kg ^ ((fr >> 1) & 3)) * 8;

    f4 acc[4][4];
#pragma unroll
    for (int m = 0; m < 4; m++)
#pragma unroll
        for (int n = 0; n < 4; n++) acc[m][n] = (f4){0.f, 0.f, 0.f, 0.f};

    const int nkt = Kd >> 5;
    for (int kt = 0; kt < nkt; ++kt) {
        const int k0 = kt * 32;

#pragma unroll
        for (int i = 0; i < 2; ++i) {
            const long r = bcol + i * 64 + w * 16 + grow;
            const int lb = i * 2048 + w * 512;
            gl16(Bhi_ + r * Kd + k0 + gcol, sBh + lb);
            if constexpr (SPLIT) gl16(Blo_ + r * Kd + k0 + gcol, sBl + lb);
        }

        if constexpr (!AF32) {
            const u16* Ahi = (const u16*)Aany;
#pragma unroll
            for (int i = 0; i < 2; ++i) {
                const long r = brow + i * 64 + w * 16 + grow;
                const int lb = i * 2048 + w * 512;
                gl16(Ahi + r * Kd + k0 + gcol, sAh + lb);
                if constexpr (SPLIT) gl16(Alo_ + r * Kd + k0 + gcol, sAl + lb);
            }
        } else {
            const float* Af = (const float*)Aany;
            const int ar = w * 8 + (l >> 3);
            const int cF = (l & 7) * 4;
#pragma unroll
            for (int j = 0; j < 4; ++j) {
                const int r = j * 32 + ar;
                const f4 v = *(const f4*)(Af + (brow + r) * (long)Kd + k0 + cF);
                u16 h[4], lw[4];
#pragma unroll
                for (int q = 0; q < 4; ++q) {
                    h[q] = f2bf(v[q]);
                    if constexpr (SPLIT) lw[q] = f2bf(v[q] - bf2f(h[q]));
                }
                *(bf4*)&sAh[r * SA + cF] = *(bf4*)h;
                if constexpr (SPLIT) *(bf4*)&sAl[r * SA + cF] = *(bf4*)lw;
            }
        }
        __syncthreads();

        bf8 fah[4], fbh[4], fal[4], fbl[4];
#pragma unroll
        for (int m = 0; m < 4; ++m) {
            if constexpr (AF32) {
                fah[m] = *(bf8*)&sAh[(wr + m * 16 + fr) * SA + kg * 8];
                if constexpr (SPLIT) fal[m] = *(bf8*)&sAl[(wr + m * 16 + fr) * SA + kg * 8];
            } else {
                fah[m] = *(bf8*)&sAh[(wr + m * 16 + fr) * 32 + kq];
                if constexpr (SPLIT) fal[m] = *(bf8*)&sAl[(wr + m * 16 + fr) * 32 + kq];
            }
            fbh[m] = *(bf8*)&sBh[(wc + m * 16 + fr) * 32 + kq];
            if constexpr (SPLIT) fbl[m] = *(bf8*)&sBl[(wc + m * 16 + fr) * 32 + kq];
        }
#pragma unroll
        for (int m = 0; m < 4; ++m)
#pragma unroll
            for (int n = 0; n < 4; ++n) {
                acc[m][n] = __builtin_amdgcn_mfma_f32_16x16x32_bf16(fah[m], fbh[n], acc[m][n], 0, 0, 0);
                if constexpr (SPLIT) {
                    acc[m][n] = __builtin_amdgcn_mfma_f32_16x16x32_bf16(fah[m], fbl[n], acc[m][n], 0, 0, 0);
                    acc[m][n] = __builtin_amdgcn_mfma_f32_16x16x32_bf16(fal[m], fbh[n], acc[m][n], 0, 0, 0);
                }
            }
        __syncthreads();
    }

#pragma unroll
    for (int n = 0; n < 4; ++n) {
        const long c = bcol + wc + n * 16 + fr;
        float bv = 0.f;
        if constexpr (EPIS) bv = bias[c];
#pragma unroll
        for (int m = 0; m < 4; ++m) {
            const long r0 = brow + wr + m * 16 + kg * 4;
#pragma unroll
            for (int r = 0; r < 4; ++r) {
                const float v = acc[m][n][r] + bv;
                if constexpr (EPIS) {
                    const u16 h = f2bf(v);
                    Chi[(r0 + r) * (long)N + c] = h;
                    Clo[(r0 + r) * (long)N + c] = f2bf(v - bf2f(h));
                } else {
                    Cf[(r0 + r) * (long)N + c] = v;
                }
            }
        }
    }
}

// ---------------------------------------------------------------------------
// Column softmax over align [N_S rows][N_Kn cols] (softmax along axis 0)
// softmax_partial is ONLINE (single pass): s = s*exp(m-mn) + exp(x-mn)
// ---------------------------------------------------------------------------
#define RCHUNK 128

__global__ __launch_bounds__(256) void softmax_partial(
    const float* __restrict__ align, float* __restrict__ pm, float* __restrict__ ps)
{
    const int col = blockIdx.x * 256 + threadIdx.x;
    const int r0 = blockIdx.y * RCHUNK;
    float m = -3.4e38f, s = 0.f;
    for (int r = 0; r < RCHUNK; r++) {
        const float x = align[(size_t)(r0 + r) * N_Kn + col];
        const float mn = fmaxf(m, x);
        s = s * __expf(m - mn) + __expf(x - mn);
        m = mn;
    }
    pm[(size_t)blockIdx.y * N_Kn + col] = m;
    ps[(size_t)blockIdx.y * N_Kn + col] = s;
}

__global__ __launch_bounds__(256) void softmax_combine(
    const float* __restrict__ pm, const float* __restrict__ ps,
    float* __restrict__ fm, float* __restrict__ fsinv)
{
    const int col = blockIdx.x * 256 + threadIdx.x;
    float m = -3.4e38f;
#pragma unroll
    for (int i = 0; i < 32; i++) m = fmaxf(m, pm[(size_t)i * N_Kn + col]);
    float s = 0.f;
#pragma unroll
    for (int i = 0; i < 32; i++)
        s += ps[(size_t)i * N_Kn + col] * __expf(pm[(size_t)i * N_Kn + col] - m);
    fm[col] = m;
    fsinv[col] = 1.f / s;
}

__global__ __launch_bounds__(256) void softmax_norm(
    float* __restrict__ align, u16* __restrict__ abf,
    const float* __restrict__ fm, const float* __restrict__ fsinv)
{
    const int col = blockIdx.x * 256 + threadIdx.x;
    const int r0 = blockIdx.y * RCHUNK;
    const float m = fm[col], si = fsinv[col];
    for (int r = 0; r < RCHUNK; r++) {
        const size_t idx = (size_t)(r0 + r) * N_Kn + col;
        const float v = __expf(align[idx] - m) * si;
        align[idx] = v;
        abf[idx] = f2bf(v);
    }
}

// ---------------------------------------------------------------------------
extern "C" void kernel_launch(void* const* d_in, const int* in_sizes, int n_in,
                              void* d_out, int out_size, void* d_ws, size_t ws_size,
                              hipStream_t stream)
{
    const float* sentences = (const float*)d_in[0];  // [4096][1024]
    const float* knowledge = (const float*)d_in[1];  // [8192][3072]
    const float* Ws = (const float*)d_in[2];         // [1024][1024]
    const float* bs = (const float*)d_in[3];         // [1024]
    const float* Wk = (const float*)d_in[4];         // [3072][1024]
    const float* bk = (const float*)d_in[5];         // [1024]

    float* out_fused = (float*)d_out;                        // [4096][3072]
    float* out_attn = (float*)d_out + (size_t)N_S * K3;      // [4096][8192]

    // workspace (~114 MB); first 64 MB reused as attn_bf16 after GEMM4
    char* w = (char*)d_ws;
    u16* attn_bf = (u16*)w;
    u16* WsT_hi = (u16*)w; w += (size_t)HID * SENT * 2;
    u16* WsT_lo = (u16*)w; w += (size_t)HID * SENT * 2;
    u16* WkT_hi = (u16*)w; w += (size_t)HID * K3 * 2;
    u16* WkT_lo = (u16*)w; w += (size_t)HID * K3 * 2;
    u16* S_hi   = (u16*)w; w += (size_t)N_S * HID * 2;
    u16* S_lo   = (u16*)w; w += (size_t)N_S * HID * 2;
    u16* K_hi   = (u16*)w; w += (size_t)N_Kn * HID * 2;
    u16* K_lo   = (u16*)w; w += (size_t)N_Kn * HID * 2;      // end = 64 MB
    u16* kT     = (u16*)w; w += (size_t)K3 * N_Kn * 2;
    float* pm   = (float*)w; w += (size_t)32 * N_Kn * 4;
    float* ps   = (float*)w; w += (size_t)32 * N_Kn * 4;
    float* fm   = (float*)w; w += (size_t)N_Kn * 4;
    float* fsv  = (float*)w; w += (size_t)N_Kn * 4;

    // 1. weight transposes (split) + knowledge^T (bf16)
    transpose_split_f32<<<dim3(HID / 32, SENT / 32), 256, 0, stream>>>(Ws, WsT_hi, WsT_lo, SENT, HID);
    transpose_split_f32<<<dim3(HID / 32, K3 / 32), 256, 0, stream>>>(Wk, WkT_hi, WkT_lo, K3, HID);
    transpose_f32_bf16<<<dim3(K3 / 32, N_Kn / 32), 256, 0, stream>>>(knowledge, kT, N_Kn, K3);

    // 2. S = sentences @ Ws + bs -> split bf16
    gemm_mfma<true, true, true><<<(HID / 128) * (N_S / 128), 256, 0, stream>>>(
        sentences, nullptr, WsT_hi, WsT_lo, nullptr, S_hi, S_lo, bs, HID, SENT, HID / 128);

    // 3. K = knowledge @ Wk + bk -> split bf16
    gemm_mfma<true, true, true><<<(HID / 128) * (N_Kn / 128), 256, 0, stream>>>(
        knowledge, nullptr, WkT_hi, WkT_lo, nullptr, K_hi, K_lo, bk, HID, K3, HID / 128);

    // 4. align = S @ K^T -> f32 into attentions slot (split, pipelined)
    gemm8s<<<(N_Kn / 128) * (N_S / 256), 512, 0, stream>>>(
        S_hi, S_lo, K_hi, K_lo, out_attn, N_Kn, HID);

    // 5. column softmax (axis 0), in place; emit bf16 attn into reused ws
    softmax_partial<<<dim3(N_Kn / 256, N_S / RCHUNK), 256, 0, stream>>>(out_attn, pm, ps);
    softmax_combine<<<dim3(N_Kn / 256), 256, 0, stream>>>(pm, ps, fm, fsv);
    softmax_norm<<<dim3(N_Kn / 256, N_S / RCHUNK), 256, 0, stream>>>(out_attn, attn_bf, fm, fsv);

    // 6. fused = attn_bf16 @ kT -> f32 (round-10/11 single-barrier schedule)
    gemm8b<<<(K3 / 192) * (N_S / 256), 512, 0, stream>>>(
        attn_bf, kT, out_fused, K3, N_Kn, K3 / 192);
}

// Round 15
// 690.975 us; speedup vs baseline: 1.1681x; 1.0295x over previous
//
#include <hip/hip_runtime.h>
#include <hip/hip_bf16.h>
#include <cstdint>
#include <cstddef>

#define N_S 4096
#define N_Kn 8192
#define HID 1024
#define SENT 1024
#define K3 3072

typedef __attribute__((ext_vector_type(4))) float f4;
typedef __attribute__((ext_vector_type(8))) short bf8;
typedef __attribute__((ext_vector_type(4))) short bf4;
typedef unsigned short u16;

__device__ __forceinline__ u16 f2bf(float x) {
    __hip_bfloat16 h = __float2bfloat16(x);   // HW RNE
    return __builtin_bit_cast(u16, h);
}
__device__ __forceinline__ float bf2f(u16 u) {
    union { unsigned int u; float f; } v; v.u = ((unsigned int)u) << 16;
    return v.f;
}

// async global->LDS, 16 bytes per lane; LDS dest = wave-uniform base + lane*16
__device__ __forceinline__ void gl16(const u16* g, u16* l) {
    __builtin_amdgcn_global_load_lds(
        (const __attribute__((address_space(1))) void*)g,
        (__attribute__((address_space(3))) void*)l, 16, 0, 0);
}

// bijective XCD swizzle (nwg % 8 == 0)
__device__ __forceinline__ int xcd_swz(int bid, int nwg) {
    const int cpx = nwg >> 3;
    return (bid & 7) * cpx + (bid >> 3);
}

#define BARR __builtin_amdgcn_s_barrier()
#define PRIO1 __builtin_amdgcn_s_setprio(1)
#define PRIO0 __builtin_amdgcn_s_setprio(0)
#define VM7  asm volatile("s_waitcnt vmcnt(7)" ::: "memory")
#define VM6  asm volatile("s_waitcnt vmcnt(6)" ::: "memory")
#define VM0  asm volatile("s_waitcnt vmcnt(0)" ::: "memory")

// ---------------------------------------------------------------------------
// Transposes
// ---------------------------------------------------------------------------
__global__ __launch_bounds__(256) void transpose_split_f32(
    const float* __restrict__ in, u16* __restrict__ hi, u16* __restrict__ lo,
    int R, int C)
{
    __shared__ float tile[32][33];
    const int bx = blockIdx.x * 32, by = blockIdx.y * 32;
    const int tx = threadIdx.x & 31, ty = threadIdx.x >> 5;
#pragma unroll
    for (int i = 0; i < 32; i += 8)
        tile[ty + i][tx] = in[(size_t)(by + ty + i) * C + bx + tx];
    __syncthreads();
#pragma unroll
    for (int i = 0; i < 32; i += 8) {
        const float v = tile[tx][ty + i];
        const u16 h = f2bf(v);
        const size_t o = (size_t)(bx + ty + i) * R + by + tx;
        hi[o] = h;
        lo[o] = f2bf(v - bf2f(h));
    }
}

__global__ __launch_bounds__(256) void transpose_f32_bf16(
    const float* __restrict__ in, u16* __restrict__ out, int R, int C)
{
    __shared__ float tile[32][33];
    const int bx = blockIdx.x * 32, by = blockIdx.y * 32;
    const int tx = threadIdx.x & 31, ty = threadIdx.x >> 5;
#pragma unroll
    for (int i = 0; i < 32; i += 8)
        tile[ty + i][tx] = in[(size_t)(by + ty + i) * C + bx + tx];
    __syncthreads();
#pragma unroll
    for (int i = 0; i < 32; i += 8)
        out[(size_t)(bx + ty + i) * R + by + tx] = f2bf(tile[tx][ty + i]);
}

// ---------------------------------------------------------------------------
// gemm8b: plain bf16 C = A @ B^T (GEMM6). BM=256, BN=192, BK=64, 512 thr
// (8 waves 4Mx2N), single-barrier 4-phase schedule, counted vmcnt(7),
// chunk-XOR swizzle, hoisted staging pointers. LDS 112 KiB.
// (Round-10/11 schedule — one-phase-ahead register prefetch REGRESSED r13.)
// ---------------------------------------------------------------------------
#define GB_LDA(buf, mh) \
  _Pragma("unroll") for (int mf_ = 0; mf_ < 2; ++mf_) \
  _Pragma("unroll") for (int kk_ = 0; kk_ < 2; ++kk_) \
    fa[mf_][kk_] = *(const bf8*)&sA[buf][(wm*64 + ((mh)*2+mf_)*16 + fr)*64 + (((kk_*4+kg) ^ (fr&7))<<3)];

#define GB_LDB(buf, nh, FB) \
  _Pragma("unroll") for (int nf_ = 0; nf_ < 3; ++nf_) \
  _Pragma("unroll") for (int kk_ = 0; kk_ < 2; ++kk_) \
    FB[nf_][kk_] = *(const bf8*)&sB[buf][(wn*96 + ((nh)*3+nf_)*16 + fr)*64 + (((kk_*4+kg) ^ (fr&7))<<3)];

#define GB_MMA(mh, nh, FB) \
  _Pragma("unroll") for (int kk_ = 0; kk_ < 2; ++kk_) \
  _Pragma("unroll") for (int mf_ = 0; mf_ < 2; ++mf_) \
  _Pragma("unroll") for (int nf_ = 0; nf_ < 3; ++nf_) \
    acc[(mh)*2+mf_][(nh)*3+nf_] = __builtin_amdgcn_mfma_f32_16x16x32_bf16( \
        fa[mf_][kk_], FB[nf_][kk_], acc[(mh)*2+mf_][(nh)*3+nf_], 0, 0, 0);

__global__ __launch_bounds__(512, 2) void gemm8b(
    const u16* __restrict__ A, const u16* __restrict__ B,
    float* __restrict__ C, int N, int Kd, int gx)
{
    __shared__ u16 sA[2][256 * 64];
    __shared__ u16 sB[2][192 * 64];

    const int swz = xcd_swz(blockIdx.x, gridDim.x);
    const int bx = swz % gx, by = swz / gx;
    const long brow = (long)by * 256, bcol = (long)bx * 192;

    const int t = threadIdx.x;
    const int w = t >> 6, l = t & 63;
    const int fr = l & 15, kg = l >> 4;
    const int wm = w >> 1;           // 0..3 : wave row block (64 rows)
    const int wn = w & 1;            // 0..1 : wave col block (96 cols)

    const int srow = t >> 3;
    const int schk = ((t & 7) ^ (srow & 7)) << 3;
    const int sldb = w << 9;

    const u16* pA0 = A + (brow +   0 + srow) * (long)Kd + schk;
    const u16* pA1 = A + (brow +  64 + srow) * (long)Kd + schk;
    const u16* pA2 = A + (brow + 128 + srow) * (long)Kd + schk;
    const u16* pA3 = A + (brow + 192 + srow) * (long)Kd + schk;
    const u16* pB0 = B + (bcol +   0 + srow) * (long)Kd + schk;
    const u16* pB1 = B + (bcol +  64 + srow) * (long)Kd + schk;
    const u16* pB2 = B + (bcol + 128 + srow) * (long)Kd + schk;

    auto stB3 = [&](int buf) {
        u16* base = &sB[buf][0];
        gl16(pB0, base + sldb);
        gl16(pB1, base + 4096 + sldb);
        gl16(pB2, base + 8192 + sldb);
    };
    auto stA4 = [&](int buf) {
        u16* base = &sA[buf][0];
        gl16(pA0, base + sldb);
        gl16(pA1, base + 4096 + sldb);
        gl16(pA2, base + 8192 + sldb);
        gl16(pA3, base + 12288 + sldb);
    };
    auto advance = [&]() {
        pA0 += 64; pA1 += 64; pA2 += 64; pA3 += 64;
        pB0 += 64; pB1 += 64; pB2 += 64;
    };

    f4 acc[4][6];
#pragma unroll
    for (int m = 0; m < 4; ++m)
#pragma unroll
        for (int n = 0; n < 6; ++n) acc[m][n] = (f4){0.f, 0.f, 0.f, 0.f};

    bf8 fa[2][2], fb0[3][2], fb1[3][2];

    const int NK = Kd >> 6;

    stB3(0); stA4(0); advance();
    stB3(1); stA4(1); advance();
    VM7;
    BARR;
    GB_LDB(0, 0, fb0);

    for (int kt = 0; kt < NK; ++kt) {
        const int buf = kt & 1;
        const bool s2 = kt + 2 < NK;
        const bool more = kt + 1 < NK;

        GB_LDA(buf, 0);
        BARR; PRIO1; GB_MMA(0, 0, fb0); PRIO0;

        GB_LDB(buf, 1, fb1);
        BARR; PRIO1; GB_MMA(0, 1, fb1); PRIO0;

        GB_LDA(buf, 1);
        if (s2) { stB3(buf); }
        BARR; PRIO1; GB_MMA(1, 0, fb0); PRIO0;

        if (s2) { stA4(buf); VM7; } else { VM0; }
        BARR;
        if (more) { GB_LDB(buf ^ 1, 0, fb0); }
        PRIO1; GB_MMA(1, 1, fb1); PRIO0;
        advance();
    }

#pragma unroll
    for (int n = 0; n < 6; ++n) {
        const long c = bcol + wn * 96 + n * 16 + fr;
#pragma unroll
        for (int m = 0; m < 4; ++m) {
            const long r0 = brow + wm * 64 + m * 16 + kg * 4;
#pragma unroll
            for (int r = 0; r < 4; ++r)
                C[(r0 + r) * (long)N + c] = acc[m][n][r];
        }
    }
}

// ---------------------------------------------------------------------------
// gemm8s: split-bf16 C = A @ B^T (GEMM4), A,B pre-split hi/lo in workspace.
// BM=256, BN=128, BK=32, 512 thr (8 waves 4Mx2N), wave tile 64x64.
// EPILOGUE also emits per-column (axis-0) partial max & exp-sum over the
// block's 256 rows -> pm/ps[16][N] (replaces softmax_partial kernel).
// ---------------------------------------------------------------------------
#define GS_LD(buf) \
  _Pragma("unroll") for (int m_ = 0; m_ < 4; ++m_) { \
    fah[m_] = *(const bf8*)&sAh[buf][(wm*64 + m_*16 + fr)*32 + kq]; \
    fal[m_] = *(const bf8*)&sAl[buf][(wm*64 + m_*16 + fr)*32 + kq]; } \
  _Pragma("unroll") for (int j_ = 0; j_ < 4; ++j_) { \
    fbh[j_] = *(const bf8*)&sBh[buf][(wn*64 + j_*16 + fr)*32 + kq]; \
    fbl[j_] = *(const bf8*)&sBl[buf][(wn*64 + j_*16 + fr)*32 + kq]; }

#define GS_MMA(nlo) \
  _Pragma("unroll") for (int m_ = 0; m_ < 4; ++m_) \
  _Pragma("unroll") for (int j_ = 0; j_ < 2; ++j_) { \
    const int n_ = (nlo)*2 + j_; \
    acc[m_][n_] = __builtin_amdgcn_mfma_f32_16x16x32_bf16(fah[m_], fbh[n_], acc[m_][n_], 0, 0, 0); \
    acc[m_][n_] = __builtin_amdgcn_mfma_f32_16x16x32_bf16(fah[m_], fbl[n_], acc[m_][n_], 0, 0, 0); \
    acc[m_][n_] = __builtin_amdgcn_mfma_f32_16x16x32_bf16(fal[m_], fbh[n_], acc[m_][n_], 0, 0, 0); }

__global__ __launch_bounds__(512, 2) void gemm8s(
    const u16* __restrict__ Ah, const u16* __restrict__ Al,
    const u16* __restrict__ Bh, const u16* __restrict__ Bl,
    float* __restrict__ C, float* __restrict__ pm, float* __restrict__ ps,
    int N, int Kd)
{
    __shared__ u16 sAh[2][8192], sAl[2][8192];
    __shared__ u16 sBh[2][4096], sBl[2][4096];

    const int bid = blockIdx.x;
    const int q = bid >> 3;
    const int by = (bid & 7) * 2 + (q & 1);   // 0..15 (XCD-paired rows)
    const int bx = q >> 1;                    // 0..63
    const long brow = (long)by * 256, bcol = (long)bx * 128;

    const int t = threadIdx.x;
    const int w = t >> 6, l = t & 63;
    const int fr = l & 15, kg = l >> 4;
    const int wm = w >> 1;                    // 0..3
    const int wn = w & 1;                     // 0..1
    const int kq = (kg ^ ((fr >> 1) & 3)) << 3;

    const int srow = t >> 2;                  // 0..127
    const int schk = ((t & 3) ^ ((t >> 3) & 3)) << 3;
    const int sldb = w << 9;

    const u16* pAh0 = Ah + (brow + srow) * (long)Kd + schk;
    const u16* pAh1 = Ah + (brow + 128 + srow) * (long)Kd + schk;
    const u16* pAl0 = Al + (brow + srow) * (long)Kd + schk;
    const u16* pAl1 = Al + (brow + 128 + srow) * (long)Kd + schk;
    const u16* pBh0 = Bh + (bcol + srow) * (long)Kd + schk;
    const u16* pBl0 = Bl + (bcol + srow) * (long)Kd + schk;

    auto stage6 = [&](int buf) {
        gl16(pBh0, &sBh[buf][sldb]);
        gl16(pBl0, &sBl[buf][sldb]);
        gl16(pAh0, &sAh[buf][sldb]);
        gl16(pAh1, &sAh[buf][4096 + sldb]);
        gl16(pAl0, &sAl[buf][sldb]);
        gl16(pAl1, &sAl[buf][4096 + sldb]);
    };
    auto advance = [&]() {
        pAh0 += 32; pAh1 += 32; pAl0 += 32; pAl1 += 32;
        pBh0 += 32; pBl0 += 32;
    };

    f4 acc[4][4];
#pragma unroll
    for (int m = 0; m < 4; ++m)
#pragma unroll
        for (int n = 0; n < 4; ++n) acc[m][n] = (f4){0.f, 0.f, 0.f, 0.f};

    bf8 fah[4], fal[4], fbh[4], fbl[4];

    const int NK = Kd >> 5;

    stage6(0); advance();
    stage6(1); advance();
    VM6;
    BARR;

    for (int kt = 0; kt < NK; ++kt) {
        const int buf = kt & 1;
        const bool s2 = kt + 2 < NK;

        GS_LD(buf);
        BARR; PRIO1; GS_MMA(0); PRIO0;

        if (s2) { stage6(buf); VM6; } else { VM0; }
        BARR;
        PRIO1; GS_MMA(1); PRIO0;
        advance();
    }

    // ---- epilogue 1: C write ----
#pragma unroll
    for (int n = 0; n < 4; ++n) {
        const long c = bcol + wn * 64 + n * 16 + fr;
#pragma unroll
        for (int m = 0; m < 4; ++m) {
            const long r0 = brow + wm * 64 + m * 16 + kg * 4;
#pragma unroll
            for (int r = 0; r < 4; ++r)
                C[(r0 + r) * (long)N + c] = acc[m][n][r];
        }
    }

    // ---- epilogue 2: per-column partial max & exp-sum over 256 rows ----
    // thread cols: c(n) = bcol + wn*64 + n*16 + fr. Reduce kg via shfl,
    // then wm via LDS scratch (sA region is dead post-K-loop).
    float* red = (float*)&sAh[0][0];   // 512 floats used
    float lmax[4];
#pragma unroll
    for (int n = 0; n < 4; ++n) {
        float m = -3.4e38f;
#pragma unroll
        for (int mm = 0; mm < 4; ++mm)
#pragma unroll
            for (int r = 0; r < 4; ++r) m = fmaxf(m, acc[mm][n][r]);
        m = fmaxf(m, __shfl_xor(m, 16, 64));
        m = fmaxf(m, __shfl_xor(m, 32, 64));
        lmax[n] = m;
    }
    BARR;
    if (kg == 0) {
#pragma unroll
        for (int n = 0; n < 4; ++n)
            red[wm * 128 + wn * 64 + n * 16 + fr] = lmax[n];
    }
    BARR;
    float bmax[4];
#pragma unroll
    for (int n = 0; n < 4; ++n) {
        const int c = wn * 64 + n * 16 + fr;
        bmax[n] = fmaxf(fmaxf(red[c], red[128 + c]),
                        fmaxf(red[256 + c], red[384 + c]));
    }
    BARR;
    float lsum[4];
#pragma unroll
    for (int n = 0; n < 4; ++n) {
        float s = 0.f;
#pragma unroll
        for (int mm = 0; mm < 4; ++mm)
#pragma unroll
            for (int r = 0; r < 4; ++r) s += __expf(acc[mm][n][r] - bmax[n]);
        s += __shfl_xor(s, 16, 64);
        s += __shfl_xor(s, 32, 64);
        lsum[n] = s;
    }
    if (kg == 0) {
#pragma unroll
        for (int n = 0; n < 4; ++n)
            red[wm * 128 + wn * 64 + n * 16 + fr] = lsum[n];
    }
    BARR;
    if (wm == 0 && kg == 0) {
#pragma unroll
        for (int n = 0; n < 4; ++n) {
            const int c = wn * 64 + n * 16 + fr;
            const float bs = red[c] + red[128 + c] + red[256 + c] + red[384 + c];
            pm[(size_t)by * N + bcol + c] = bmax[n];
            ps[(size_t)by * N + bcol + c] = bs;
        }
    }
}

// ---------------------------------------------------------------------------
// gemm_mfma: C[M][N] = A[M][K] @ B^T (+ bias); SPLIT/AF32/EPIS (GEMM2/3).
// Block order: XCD chunk -> 4x4 supertiles.
// ---------------------------------------------------------------------------
template <bool SPLIT, bool AF32, bool EPIS>
__global__ __launch_bounds__(256) void gemm_mfma(
    const void* __restrict__ Aany, const u16* __restrict__ Alo_,
    const u16* __restrict__ Bhi_, const u16* __restrict__ Blo_,
    float* __restrict__ Cf, u16* __restrict__ Chi, u16* __restrict__ Clo,
    const float* __restrict__ bias, int N, int Kd, int gx)
{
    constexpr int SA = AF32 ? 48 : 32;
    __shared__ u16 sAh[128 * SA];
    __shared__ u16 sAl[SPLIT ? 128 * SA : 8];
    __shared__ u16 sBh[128 * 32];
    __shared__ u16 sBl[SPLIT ? 128 * 32 : 8];

    const int swz = xcd_swz(blockIdx.x, gridDim.x);
    const int nst_x = gx >> 2;
    const int st = swz >> 4, off = swz & 15;
    const int bxi = (st % nst_x) * 4 + (off & 3);
    const int byi = (st / nst_x) * 4 + (off >> 2);

    const int t = threadIdx.x;
    const int w = t >> 6;
    const int l = t & 63;
    const long brow = (long)byi * 128;
    const long bcol = (long)bxi * 128;

    const int grow = l >> 2;
    const int gcol = ((l & 3) ^ ((l >> 3) & 3)) * 8;

    const int wr = (w >> 1) * 64;
    const int wc = (w & 1) * 64;
    const int fr = l & 15;
    const int kg = l >> 4;
    const int kq = (kg ^ ((fr >> 1) & 3)) * 8;

    f4 acc[4][4];
#pragma unroll
    for (int m = 0; m < 4; m++)
#pragma unroll
        for (int n = 0; n < 4; n++) acc[m][n] = (f4){0.f, 0.f, 0.f, 0.f};

    const int nkt = Kd >> 5;
    for (int kt = 0; kt < nkt; ++kt) {
        const int k0 = kt * 32;

#pragma unroll
        for (int i = 0; i < 2; ++i) {
            const long r = bcol + i * 64 + w * 16 + grow;
            const int lb = i * 2048 + w * 512;
            gl16(Bhi_ + r * Kd + k0 + gcol, sBh + lb);
            if constexpr (SPLIT) gl16(Blo_ + r * Kd + k0 + gcol, sBl + lb);
        }

        if constexpr (!AF32) {
            const u16* Ahi = (const u16*)Aany;
#pragma unroll
            for (int i = 0; i < 2; ++i) {
                const long r = brow + i * 64 + w * 16 + grow;
                const int lb = i * 2048 + w * 512;
                gl16(Ahi + r * Kd + k0 + gcol, sAh + lb);
                if constexpr (SPLIT) gl16(Alo_ + r * Kd + k0 + gcol, sAl + lb);
            }
        } else {
            const float* Af = (const float*)Aany;
            const int ar = w * 8 + (l >> 3);
            const int cF = (l & 7) * 4;
#pragma unroll
            for (int j = 0; j < 4; ++j) {
                const int r = j * 32 + ar;
                const f4 v = *(const f4*)(Af + (brow + r) * (long)Kd + k0 + cF);
                u16 h[4], lw[4];
#pragma unroll
                for (int q = 0; q < 4; ++q) {
                    h[q] = f2bf(v[q]);
                    if constexpr (SPLIT) lw[q] = f2bf(v[q] - bf2f(h[q]));
                }
                *(bf4*)&sAh[r * SA + cF] = *(bf4*)h;
                if constexpr (SPLIT) *(bf4*)&sAl[r * SA + cF] = *(bf4*)lw;
            }
        }
        __syncthreads();

        bf8 fah[4], fbh[4], fal[4], fbl[4];
#pragma unroll
        for (int m = 0; m < 4; ++m) {
            if constexpr (AF32) {
                fah[m] = *(bf8*)&sAh[(wr + m * 16 + fr) * SA + kg * 8];
                if constexpr (SPLIT) fal[m] = *(bf8*)&sAl[(wr + m * 16 + fr) * SA + kg * 8];
            } else {
                fah[m] = *(bf8*)&sAh[(wr + m * 16 + fr) * 32 + kq];
                if constexpr (SPLIT) fal[m] = *(bf8*)&sAl[(wr + m * 16 + fr) * 32 + kq];
            }
            fbh[m] = *(bf8*)&sBh[(wc + m * 16 + fr) * 32 + kq];
            if constexpr (SPLIT) fbl[m] = *(bf8*)&sBl[(wc + m * 16 + fr) * 32 + kq];
        }
#pragma unroll
        for (int m = 0; m < 4; ++m)
#pragma unroll
            for (int n = 0; n < 4; ++n) {
                acc[m][n] = __builtin_amdgcn_mfma_f32_16x16x32_bf16(fah[m], fbh[n], acc[m][n], 0, 0, 0);
                if constexpr (SPLIT) {
                    acc[m][n] = __builtin_amdgcn_mfma_f32_16x16x32_bf16(fah[m], fbl[n], acc[m][n], 0, 0, 0);
                    acc[m][n] = __builtin_amdgcn_mfma_f32_16x16x32_bf16(fal[m], fbh[n], acc[m][n], 0, 0, 0);
                }
            }
        __syncthreads();
    }

#pragma unroll
    for (int n = 0; n < 4; ++n) {
        const long c = bcol + wc + n * 16 + fr;
        float bv = 0.f;
        if constexpr (EPIS) bv = bias[c];
#pragma unroll
        for (int m = 0; m < 4; ++m) {
            const long r0 = brow + wr + m * 16 + kg * 4;
#pragma unroll
            for (int r = 0; r < 4; ++r) {
                const float v = acc[m][n][r] + bv;
                if constexpr (EPIS) {
                    const u16 h = f2bf(v);
                    Chi[(r0 + r) * (long)N + c] = h;
                    Clo[(r0 + r) * (long)N + c] = f2bf(v - bf2f(h));
                } else {
                    Cf[(r0 + r) * (long)N + c] = v;
                }
            }
        }
    }
}

// ---------------------------------------------------------------------------
// Column softmax over align [N_S rows][N_Kn cols] (softmax along axis 0).
// Partials now come from gemm8s's epilogue: pm/ps[16][N_Kn] (256-row chunks).
// ---------------------------------------------------------------------------
#define RCHUNK 128

__global__ __launch_bounds__(256) void softmax_combine(
    const float* __restrict__ pm, const float* __restrict__ ps,
    float* __restrict__ fm, float* __restrict__ fsinv)
{
    const int col = blockIdx.x * 256 + threadIdx.x;
    float m = -3.4e38f;
#pragma unroll
    for (int i = 0; i < 16; i++) m = fmaxf(m, pm[(size_t)i * N_Kn + col]);
    float s = 0.f;
#pragma unroll
    for (int i = 0; i < 16; i++)
        s += ps[(size_t)i * N_Kn + col] * __expf(pm[(size_t)i * N_Kn + col] - m);
    fm[col] = m;
    fsinv[col] = 1.f / s;
}

__global__ __launch_bounds__(256) void softmax_norm(
    float* __restrict__ align, u16* __restrict__ abf,
    const float* __restrict__ fm, const float* __restrict__ fsinv)
{
    const int col = blockIdx.x * 256 + threadIdx.x;
    const int r0 = blockIdx.y * RCHUNK;
    const float m = fm[col], si = fsinv[col];
    for (int r = 0; r < RCHUNK; r++) {
        const size_t idx = (size_t)(r0 + r) * N_Kn + col;
        const float v = __expf(align[idx] - m) * si;
        align[idx] = v;
        abf[idx] = f2bf(v);
    }
}

// ---------------------------------------------------------------------------
extern "C" void kernel_launch(void* const* d_in, const int* in_sizes, int n_in,
                              void* d_out, int out_size, void* d_ws, size_t ws_size,
                              hipStream_t stream)
{
    const float* sentences = (const float*)d_in[0];  // [4096][1024]
    const float* knowledge = (const float*)d_in[1];  // [8192][3072]
    const float* Ws = (const float*)d_in[2];         // [1024][1024]
    const float* bs = (const float*)d_in[3];         // [1024]
    const float* Wk = (const float*)d_in[4];         // [3072][1024]
    const float* bk = (const float*)d_in[5];         // [1024]

    float* out_fused = (float*)d_out;                        // [4096][3072]
    float* out_attn = (float*)d_out + (size_t)N_S * K3;      // [4096][8192]

    // workspace (~114 MB); first 64 MB reused as attn_bf16 after GEMM4
    char* w = (char*)d_ws;
    u16* attn_bf = (u16*)w;
    u16* WsT_hi = (u16*)w; w += (size_t)HID * SENT * 2;
    u16* WsT_lo = (u16*)w; w += (size_t)HID * SENT * 2;
    u16* WkT_hi = (u16*)w; w += (size_t)HID * K3 * 2;
    u16* WkT_lo = (u16*)w; w += (size_t)HID * K3 * 2;
    u16* S_hi   = (u16*)w; w += (size_t)N_S * HID * 2;
    u16* S_lo   = (u16*)w; w += (size_t)N_S * HID * 2;
    u16* K_hi   = (u16*)w; w += (size_t)N_Kn * HID * 2;
    u16* K_lo   = (u16*)w; w += (size_t)N_Kn * HID * 2;      // end = 64 MB
    u16* kT     = (u16*)w; w += (size_t)K3 * N_Kn * 2;
    float* pm   = (float*)w; w += (size_t)16 * N_Kn * 4;
    float* ps   = (float*)w; w += (size_t)16 * N_Kn * 4;
    float* fm   = (float*)w; w += (size_t)N_Kn * 4;
    float* fsv  = (float*)w; w += (size_t)N_Kn * 4;

    // 1. weight transposes (split) + knowledge^T (bf16)
    transpose_split_f32<<<dim3(HID / 32, SENT / 32), 256, 0, stream>>>(Ws, WsT_hi, WsT_lo, SENT, HID);
    transpose_split_f32<<<dim3(HID / 32, K3 / 32), 256, 0, stream>>>(Wk, WkT_hi, WkT_lo, K3, HID);
    transpose_f32_bf16<<<dim3(K3 / 32, N_Kn / 32), 256, 0, stream>>>(knowledge, kT, N_Kn, K3);

    // 2. S = sentences @ Ws + bs -> split bf16
    gemm_mfma<true, true, true><<<(HID / 128) * (N_S / 128), 256, 0, stream>>>(
        sentences, nullptr, WsT_hi, WsT_lo, nullptr, S_hi, S_lo, bs, HID, SENT, HID / 128);

    // 3. K = knowledge @ Wk + bk -> split bf16
    gemm_mfma<true, true, true><<<(HID / 128) * (N_Kn / 128), 256, 0, stream>>>(
        knowledge, nullptr, WkT_hi, WkT_lo, nullptr, K_hi, K_lo, bk, HID, K3, HID / 128);

    // 4. align = S @ K^T -> f32 into attentions slot; epilogue emits
    //    per-256-row-column partials pm/ps (softmax_partial is gone)
    gemm8s<<<(N_Kn / 128) * (N_S / 256), 512, 0, stream>>>(
        S_hi, S_lo, K_hi, K_lo, out_attn, pm, ps, N_Kn, HID);

    // 5. column softmax finish (axis 0), in place; emit bf16 attn
    softmax_combine<<<dim3(N_Kn / 256), 256, 0, stream>>>(pm, ps, fm, fsv);
    softmax_norm<<<dim3(N_Kn / 256, N_S / RCHUNK), 256, 0, stream>>>(out_attn, attn_bf, fm, fsv);

    // 6. fused = attn_bf16 @ kT -> f32
    gemm8b<<<(K3 / 192) * (N_S / 256), 512, 0, stream>>>(
        attn_bf, kT, out_fused, K3, N_Kn, K3 / 192);
}

// Round 16
// 679.495 us; speedup vs baseline: 1.1878x; 1.0169x over previous
//
#include <hip/hip_runtime.h>
#include <hip/hip_bf16.h>
#include <cstdint>
#include <cstddef>

#define N_S 4096
#define N_Kn 8192
#define HID 1024
#define SENT 1024
#define K3 3072

typedef __attribute__((ext_vector_type(4))) float f4;
typedef __attribute__((ext_vector_type(8))) short bf8;
typedef __attribute__((ext_vector_type(4))) short bf4;
typedef unsigned short u16;

__device__ __forceinline__ u16 f2bf(float x) {
    __hip_bfloat16 h = __float2bfloat16(x);   // HW RNE
    return __builtin_bit_cast(u16, h);
}
__device__ __forceinline__ float bf2f(u16 u) {
    union { unsigned int u; float f; } v; v.u = ((unsigned int)u) << 16;
    return v.f;
}

// async global->LDS, 16 bytes per lane; LDS dest = wave-uniform base + lane*16
__device__ __forceinline__ void gl16(const u16* g, u16* l) {
    __builtin_amdgcn_global_load_lds(
        (const __attribute__((address_space(1))) void*)g,
        (__attribute__((address_space(3))) void*)l, 16, 0, 0);
}

// bijective XCD swizzle (nwg % 8 == 0)
__device__ __forceinline__ int xcd_swz(int bid, int nwg) {
    const int cpx = nwg >> 3;
    return (bid & 7) * cpx + (bid >> 3);
}

#define BARR __builtin_amdgcn_s_barrier()
#define PRIO1 __builtin_amdgcn_s_setprio(1)
#define PRIO0 __builtin_amdgcn_s_setprio(0)
#define VM8  asm volatile("s_waitcnt vmcnt(8)" ::: "memory")
#define VM7  asm volatile("s_waitcnt vmcnt(7)" ::: "memory")
#define VM6  asm volatile("s_waitcnt vmcnt(6)" ::: "memory")
#define VM2  asm volatile("s_waitcnt vmcnt(2)" ::: "memory")
#define VM0  asm volatile("s_waitcnt vmcnt(0)" ::: "memory")
#define LGKM0 asm volatile("s_waitcnt lgkmcnt(0)" ::: "memory")

// ---------------------------------------------------------------------------
// Transposes
// ---------------------------------------------------------------------------
__global__ __launch_bounds__(256) void transpose_split_f32(
    const float* __restrict__ in, u16* __restrict__ hi, u16* __restrict__ lo,
    int R, int C)
{
    __shared__ float tile[32][33];
    const int bx = blockIdx.x * 32, by = blockIdx.y * 32;
    const int tx = threadIdx.x & 31, ty = threadIdx.x >> 5;
#pragma unroll
    for (int i = 0; i < 32; i += 8)
        tile[ty + i][tx] = in[(size_t)(by + ty + i) * C + bx + tx];
    __syncthreads();
#pragma unroll
    for (int i = 0; i < 32; i += 8) {
        const float v = tile[tx][ty + i];
        const u16 h = f2bf(v);
        const size_t o = (size_t)(bx + ty + i) * R + by + tx;
        hi[o] = h;
        lo[o] = f2bf(v - bf2f(h));
    }
}

__global__ __launch_bounds__(256) void transpose_f32_bf16(
    const float* __restrict__ in, u16* __restrict__ out, int R, int C)
{
    __shared__ float tile[32][33];
    const int bx = blockIdx.x * 32, by = blockIdx.y * 32;
    const int tx = threadIdx.x & 31, ty = threadIdx.x >> 5;
#pragma unroll
    for (int i = 0; i < 32; i += 8)
        tile[ty + i][tx] = in[(size_t)(by + ty + i) * C + bx + tx];
    __syncthreads();
#pragma unroll
    for (int i = 0; i < 32; i += 8)
        out[(size_t)(bx + ty + i) * R + by + tx] = f2bf(tile[tx][ty + i]);
}

// ---------------------------------------------------------------------------
// gemm8b: plain bf16 C = A @ B^T (GEMM6). BM=256, BN=192, BK=64, 512 thr
// (8 waves 4Mx2N), single-barrier 4-phase schedule, counted vmcnt(7),
// chunk-XOR swizzle, hoisted staging pointers. LDS 112 KiB.
// ---------------------------------------------------------------------------
#define GB_LDA(buf, mh) \
  _Pragma("unroll") for (int mf_ = 0; mf_ < 2; ++mf_) \
  _Pragma("unroll") for (int kk_ = 0; kk_ < 2; ++kk_) \
    fa[mf_][kk_] = *(const bf8*)&sA[buf][(wm*64 + ((mh)*2+mf_)*16 + fr)*64 + (((kk_*4+kg) ^ (fr&7))<<3)];

#define GB_LDB(buf, nh, FB) \
  _Pragma("unroll") for (int nf_ = 0; nf_ < 3; ++nf_) \
  _Pragma("unroll") for (int kk_ = 0; kk_ < 2; ++kk_) \
    FB[nf_][kk_] = *(const bf8*)&sB[buf][(wn*96 + ((nh)*3+nf_)*16 + fr)*64 + (((kk_*4+kg) ^ (fr&7))<<3)];

#define GB_MMA(mh, nh, FB) \
  _Pragma("unroll") for (int kk_ = 0; kk_ < 2; ++kk_) \
  _Pragma("unroll") for (int mf_ = 0; mf_ < 2; ++mf_) \
  _Pragma("unroll") for (int nf_ = 0; nf_ < 3; ++nf_) \
    acc[(mh)*2+mf_][(nh)*3+nf_] = __builtin_amdgcn_mfma_f32_16x16x32_bf16( \
        fa[mf_][kk_], FB[nf_][kk_], acc[(mh)*2+mf_][(nh)*3+nf_], 0, 0, 0);

__global__ __launch_bounds__(512, 2) void gemm8b(
    const u16* __restrict__ A, const u16* __restrict__ B,
    float* __restrict__ C, int N, int Kd, int gx)
{
    __shared__ u16 sA[2][256 * 64];
    __shared__ u16 sB[2][192 * 64];

    const int swz = xcd_swz(blockIdx.x, gridDim.x);
    const int bx = swz % gx, by = swz / gx;
    const long brow = (long)by * 256, bcol = (long)bx * 192;

    const int t = threadIdx.x;
    const int w = t >> 6, l = t & 63;
    const int fr = l & 15, kg = l >> 4;
    const int wm = w >> 1;
    const int wn = w & 1;

    const int srow = t >> 3;
    const int schk = ((t & 7) ^ (srow & 7)) << 3;
    const int sldb = w << 9;

    const u16* pA0 = A + (brow +   0 + srow) * (long)Kd + schk;
    const u16* pA1 = A + (brow +  64 + srow) * (long)Kd + schk;
    const u16* pA2 = A + (brow + 128 + srow) * (long)Kd + schk;
    const u16* pA3 = A + (brow + 192 + srow) * (long)Kd + schk;
    const u16* pB0 = B + (bcol +   0 + srow) * (long)Kd + schk;
    const u16* pB1 = B + (bcol +  64 + srow) * (long)Kd + schk;
    const u16* pB2 = B + (bcol + 128 + srow) * (long)Kd + schk;

    auto stB3 = [&](int buf) {
        u16* base = &sB[buf][0];
        gl16(pB0, base + sldb);
        gl16(pB1, base + 4096 + sldb);
        gl16(pB2, base + 8192 + sldb);
    };
    auto stA4 = [&](int buf) {
        u16* base = &sA[buf][0];
        gl16(pA0, base + sldb);
        gl16(pA1, base + 4096 + sldb);
        gl16(pA2, base + 8192 + sldb);
        gl16(pA3, base + 12288 + sldb);
    };
    auto advance = [&]() {
        pA0 += 64; pA1 += 64; pA2 += 64; pA3 += 64;
        pB0 += 64; pB1 += 64; pB2 += 64;
    };

    f4 acc[4][6];
#pragma unroll
    for (int m = 0; m < 4; ++m)
#pragma unroll
        for (int n = 0; n < 6; ++n) acc[m][n] = (f4){0.f, 0.f, 0.f, 0.f};

    bf8 fa[2][2], fb0[3][2], fb1[3][2];

    const int NK = Kd >> 6;

    stB3(0); stA4(0); advance();
    stB3(1); stA4(1); advance();
    VM7;
    BARR;
    GB_LDB(0, 0, fb0);

    for (int kt = 0; kt < NK; ++kt) {
        const int buf = kt & 1;
        const bool s2 = kt + 2 < NK;
        const bool more = kt + 1 < NK;

        GB_LDA(buf, 0);
        BARR; PRIO1; GB_MMA(0, 0, fb0); PRIO0;

        GB_LDB(buf, 1, fb1);
        BARR; PRIO1; GB_MMA(0, 1, fb1); PRIO0;

        GB_LDA(buf, 1);
        if (s2) { stB3(buf); }
        BARR; PRIO1; GB_MMA(1, 0, fb0); PRIO0;

        if (s2) { stA4(buf); VM7; } else { VM0; }
        BARR;
        if (more) { GB_LDB(buf ^ 1, 0, fb0); }
        PRIO1; GB_MMA(1, 1, fb1); PRIO0;
        advance();
    }

#pragma unroll
    for (int n = 0; n < 6; ++n) {
        const long c = bcol + wn * 96 + n * 16 + fr;
#pragma unroll
        for (int m = 0; m < 4; ++m) {
            const long r0 = brow + wm * 64 + m * 16 + kg * 4;
#pragma unroll
            for (int r = 0; r < 4; ++r)
                C[(r0 + r) * (long)N + c] = acc[m][n][r];
        }
    }
}

// ---------------------------------------------------------------------------
// Shared split-GEMM phase macros (gemm8s / gemm8f)
// ---------------------------------------------------------------------------
#define GS_LD(buf) \
  _Pragma("unroll") for (int m_ = 0; m_ < 4; ++m_) { \
    fah[m_] = *(const bf8*)&sAh[buf][(wm*64 + m_*16 + fr)*32 + kq]; \
    fal[m_] = *(const bf8*)&sAl[buf][(wm*64 + m_*16 + fr)*32 + kq]; } \
  _Pragma("unroll") for (int j_ = 0; j_ < 4; ++j_) { \
    fbh[j_] = *(const bf8*)&sBh[buf][(wn*64 + j_*16 + fr)*32 + kq]; \
    fbl[j_] = *(const bf8*)&sBl[buf][(wn*64 + j_*16 + fr)*32 + kq]; }

#define GS_MMA(nlo) \
  _Pragma("unroll") for (int m_ = 0; m_ < 4; ++m_) \
  _Pragma("unroll") for (int j_ = 0; j_ < 2; ++j_) { \
    const int n_ = (nlo)*2 + j_; \
    acc[m_][n_] = __builtin_amdgcn_mfma_f32_16x16x32_bf16(fah[m_], fbh[n_], acc[m_][n_], 0, 0, 0); \
    acc[m_][n_] = __builtin_amdgcn_mfma_f32_16x16x32_bf16(fah[m_], fbl[n_], acc[m_][n_], 0, 0, 0); \
    acc[m_][n_] = __builtin_amdgcn_mfma_f32_16x16x32_bf16(fal[m_], fbh[n_], acc[m_][n_], 0, 0, 0); }

// ---------------------------------------------------------------------------
// gemm8s: split-bf16 C = A @ B^T (GEMM4), A,B pre-split hi/lo in workspace.
// BM=256, BN=128, BK=32, 512 thr (8 waves 4Mx2N). Epilogue emits per-column
// partial max & exp-sum over the block's 256 rows -> pm/ps[16][N].
// ---------------------------------------------------------------------------
__global__ __launch_bounds__(512, 2) void gemm8s(
    const u16* __restrict__ Ah, const u16* __restrict__ Al,
    const u16* __restrict__ Bh, const u16* __restrict__ Bl,
    float* __restrict__ C, float* __restrict__ pm, float* __restrict__ ps,
    int N, int Kd)
{
    __shared__ u16 sAh[2][8192], sAl[2][8192];
    __shared__ u16 sBh[2][4096], sBl[2][4096];

    const int bid = blockIdx.x;
    const int q = bid >> 3;
    const int by = (bid & 7) * 2 + (q & 1);   // 0..15
    const int bx = q >> 1;                    // 0..63
    const long brow = (long)by * 256, bcol = (long)bx * 128;

    const int t = threadIdx.x;
    const int w = t >> 6, l = t & 63;
    const int fr = l & 15, kg = l >> 4;
    const int wm = w >> 1;
    const int wn = w & 1;
    const int kq = (kg ^ ((fr >> 1) & 3)) << 3;

    const int srow = t >> 2;
    const int schk = ((t & 3) ^ ((t >> 3) & 3)) << 3;
    const int sldb = w << 9;

    const u16* pAh0 = Ah + (brow + srow) * (long)Kd + schk;
    const u16* pAh1 = Ah + (brow + 128 + srow) * (long)Kd + schk;
    const u16* pAl0 = Al + (brow + srow) * (long)Kd + schk;
    const u16* pAl1 = Al + (brow + 128 + srow) * (long)Kd + schk;
    const u16* pBh0 = Bh + (bcol + srow) * (long)Kd + schk;
    const u16* pBl0 = Bl + (bcol + srow) * (long)Kd + schk;

    auto stage6 = [&](int buf) {
        gl16(pBh0, &sBh[buf][sldb]);
        gl16(pBl0, &sBl[buf][sldb]);
        gl16(pAh0, &sAh[buf][sldb]);
        gl16(pAh1, &sAh[buf][4096 + sldb]);
        gl16(pAl0, &sAl[buf][sldb]);
        gl16(pAl1, &sAl[buf][4096 + sldb]);
    };
    auto advance = [&]() {
        pAh0 += 32; pAh1 += 32; pAl0 += 32; pAl1 += 32;
        pBh0 += 32; pBl0 += 32;
    };

    f4 acc[4][4];
#pragma unroll
    for (int m = 0; m < 4; ++m)
#pragma unroll
        for (int n = 0; n < 4; ++n) acc[m][n] = (f4){0.f, 0.f, 0.f, 0.f};

    bf8 fah[4], fal[4], fbh[4], fbl[4];

    const int NK = Kd >> 5;

    stage6(0); advance();
    stage6(1); advance();
    VM6;
    BARR;

    for (int kt = 0; kt < NK; ++kt) {
        const int buf = kt & 1;
        const bool s2 = kt + 2 < NK;

        GS_LD(buf);
        BARR; PRIO1; GS_MMA(0); PRIO0;

        if (s2) { stage6(buf); VM6; } else { VM0; }
        BARR;
        PRIO1; GS_MMA(1); PRIO0;
        advance();
    }

    // ---- epilogue 1: C write ----
#pragma unroll
    for (int n = 0; n < 4; ++n) {
        const long c = bcol + wn * 64 + n * 16 + fr;
#pragma unroll
        for (int m = 0; m < 4; ++m) {
            const long r0 = brow + wm * 64 + m * 16 + kg * 4;
#pragma unroll
            for (int r = 0; r < 4; ++r)
                C[(r0 + r) * (long)N + c] = acc[m][n][r];
        }
    }

    // ---- epilogue 2: per-column partial max & exp-sum over 256 rows ----
    float* red = (float*)&sAh[0][0];
    float lmax[4];
#pragma unroll
    for (int n = 0; n < 4; ++n) {
        float m = -3.4e38f;
#pragma unroll
        for (int mm = 0; mm < 4; ++mm)
#pragma unroll
            for (int r = 0; r < 4; ++r) m = fmaxf(m, acc[mm][n][r]);
        m = fmaxf(m, __shfl_xor(m, 16, 64));
        m = fmaxf(m, __shfl_xor(m, 32, 64));
        lmax[n] = m;
    }
    BARR;
    if (kg == 0) {
#pragma unroll
        for (int n = 0; n < 4; ++n)
            red[wm * 128 + wn * 64 + n * 16 + fr] = lmax[n];
    }
    BARR;
    float bmax[4];
#pragma unroll
    for (int n = 0; n < 4; ++n) {
        const int c = wn * 64 + n * 16 + fr;
        bmax[n] = fmaxf(fmaxf(red[c], red[128 + c]),
                        fmaxf(red[256 + c], red[384 + c]));
    }
    BARR;
    float lsum[4];
#pragma unroll
    for (int n = 0; n < 4; ++n) {
        float s = 0.f;
#pragma unroll
        for (int mm = 0; mm < 4; ++mm)
#pragma unroll
            for (int r = 0; r < 4; ++r) s += __expf(acc[mm][n][r] - bmax[n]);
        s += __shfl_xor(s, 16, 64);
        s += __shfl_xor(s, 32, 64);
        lsum[n] = s;
    }
    if (kg == 0) {
#pragma unroll
        for (int n = 0; n < 4; ++n)
            red[wm * 128 + wn * 64 + n * 16 + fr] = lsum[n];
    }
    BARR;
    if (wm == 0 && kg == 0) {
#pragma unroll
        for (int n = 0; n < 4; ++n) {
            const int c = wn * 64 + n * 16 + fr;
            const float bs = red[c] + red[128 + c] + red[256 + c] + red[384 + c];
            pm[(size_t)by * N + bcol + c] = bmax[n];
            ps[(size_t)by * N + bcol + c] = bs;
        }
    }
}

// ---------------------------------------------------------------------------
// gemm8f: split-bf16 C = A @ B^T for f32 A (GEMM3: K = knowledge @ Wk + bk).
// Same schedule as gemm8s; A is reg-staged (T14 issue-early/write-late):
// f4 loads for t+2 issue in phA, phB: 2 B-gl16, vmcnt(2) (drains the f4s
// AND t+1's B-gl16s), cvt to hi/lo, ds_write_b128 swizzled, lgkmcnt(0), BARR.
// M=8192 fixed by grid map (256 blocks: by=((bid&7)<<2)|(q&3), bx=q>>2).
// Epilogue: + bias, split hi/lo store.
// ---------------------------------------------------------------------------
__global__ __launch_bounds__(512, 2) void gemm8f(
    const float* __restrict__ Af, const u16* __restrict__ Bh, const u16* __restrict__ Bl,
    u16* __restrict__ Chi, u16* __restrict__ Clo, const float* __restrict__ bias,
    int N, int Kd)
{
    __shared__ u16 sAh[2][8192], sAl[2][8192];
    __shared__ u16 sBh[2][4096], sBl[2][4096];

    const int bid = blockIdx.x;
    const int q = bid >> 3;
    const int by = ((bid & 7) << 2) | (q & 3);  // 0..31
    const int bx = q >> 2;                      // 0..7
    const long brow = (long)by * 256, bcol = (long)bx * 128;

    const int t = threadIdx.x;
    const int w = t >> 6, l = t & 63;
    const int fr = l & 15, kg = l >> 4;
    const int wm = w >> 1;
    const int wn = w & 1;
    const int kq = (kg ^ ((fr >> 1) & 3)) << 3;

    // B staging (gl16, 128 rows)
    const int srow = t >> 2;
    const int schk = ((t & 3) ^ ((t >> 3) & 3)) << 3;
    const int sldb = w << 9;
    const u16* pBh0 = Bh + (bcol + srow) * (long)Kd + schk;
    const u16* pBl0 = Bl + (bcol + srow) * (long)Kd + schk;

    // A reg-staging: thread t owns chunk c1=t (rows 0..127) and c2=t+512
    // (rows 128..255); 8 f32 each; LDS chunk swizzle = chunk ^ ((row>>1)&3)
    // (row bits 1,2 of both c1,c2 equal bits 1,2 of (t>>2)) -> same schk.
    const float* pA0 = Af + (brow + srow) * (long)Kd + (t & 3) * 8;
    const float* pA1 = Af + (brow + 128 + srow) * (long)Kd + (t & 3) * 8;
    const int adst = srow * 32 + schk;          // +4096 for c2

    auto cvt_write = [&](int buf, int dst, const f4& x0, const f4& x1) {
        float xv[8];
        *(f4*)&xv[0] = x0; *(f4*)&xv[4] = x1;
        u16 h[8], lw[8];
#pragma unroll
        for (int j = 0; j < 8; ++j) {
            h[j] = f2bf(xv[j]);
            lw[j] = f2bf(xv[j] - bf2f(h[j]));
        }
        *(bf8*)&sAh[buf][dst] = *(bf8*)h;
        *(bf8*)&sAl[buf][dst] = *(bf8*)lw;
    };

    f4 acc[4][4];
#pragma unroll
    for (int m = 0; m < 4; ++m)
#pragma unroll
        for (int n = 0; n < 4; ++n) acc[m][n] = (f4){0.f, 0.f, 0.f, 0.f};

    bf8 fah[4], fal[4], fbh[4], fbl[4];

    const int NK = Kd >> 5;

    // prologue: issue A(t0) f4x4, B(t0) gl16x2, A(t1) f4x4, B(t1) gl16x2
    {
        f4 a00 = *(const f4*)(pA0);      f4 a01 = *(const f4*)(pA0 + 4);
        f4 a10 = *(const f4*)(pA1);      f4 a11 = *(const f4*)(pA1 + 4);
        gl16(pBh0, &sBh[0][sldb]); gl16(pBl0, &sBl[0][sldb]);
        f4 b00 = *(const f4*)(pA0 + 32); f4 b01 = *(const f4*)(pA0 + 36);
        f4 b10 = *(const f4*)(pA1 + 32); f4 b11 = *(const f4*)(pA1 + 36);
        gl16(pBh0 + 32, &sBh[1][sldb]); gl16(pBl0 + 32, &sBl[1][sldb]);
        VM8;   // drains A(t0) f4s (4 oldest of 12)
        cvt_write(0, adst, a00, a01);
        cvt_write(0, adst + 4096, a10, a11);
        VM2;   // drains B(t0), A(t1); leaves B(t1)x2
        cvt_write(1, adst, b00, b01);
        cvt_write(1, adst + 4096, b10, b11);
        LGKM0;
        BARR;
        pA0 += 64; pA1 += 64; pBh0 += 64; pBl0 += 64;
    }

    for (int kt = 0; kt < NK; ++kt) {
        const int buf = kt & 1;
        const bool s2 = kt + 2 < NK;

        // phA: frag reads; issue A(t+2) f4 loads (hide under MMA(0))
        GS_LD(buf);
        f4 x0, x1, y0, y1;
        if (s2) {
            x0 = *(const f4*)(pA0); x1 = *(const f4*)(pA0 + 4);
            y0 = *(const f4*)(pA1); y1 = *(const f4*)(pA1 + 4);
        }
        BARR; PRIO1; GS_MMA(0); PRIO0;

        // phB: B(t+2) gl16; vmcnt(2) drains A(t+2) f4s + B(t+1) gl16s;
        // cvt+ds_write A(t+2) into buf (reads retired at phA BARR); lgkm0
        if (s2) {
            gl16(pBh0, &sBh[buf][sldb]);
            gl16(pBl0, &sBl[buf][sldb]);
            VM2;
            cvt_write(buf, adst, x0, x1);
            cvt_write(buf, adst + 4096, y0, y1);
            LGKM0;
        } else {
            VM0;
        }
        BARR;
        PRIO1; GS_MMA(1); PRIO0;
        pA0 += 32; pA1 += 32; pBh0 += 32; pBl0 += 32;
    }

    // epilogue: + bias, split hi/lo store
#pragma unroll
    for (int n = 0; n < 4; ++n) {
        const long c = bcol + wn * 64 + n * 16 + fr;
        const float bv = bias[c];
#pragma unroll
        for (int m = 0; m < 4; ++m) {
            const long r0 = brow + wm * 64 + m * 16 + kg * 4;
#pragma unroll
            for (int r = 0; r < 4; ++r) {
                const float v = acc[m][n][r] + bv;
                const u16 h = f2bf(v);
                Chi[(r0 + r) * (long)N + c] = h;
                Clo[(r0 + r) * (long)N + c] = f2bf(v - bf2f(h));
            }
        }
    }
}

// ---------------------------------------------------------------------------
// gemm_mfma: C[M][N] = A[M][K] @ B^T (+ bias); SPLIT/AF32/EPIS (GEMM2).
// Block order: XCD chunk -> 4x4 supertiles.
// ---------------------------------------------------------------------------
template <bool SPLIT, bool AF32, bool EPIS>
__global__ __launch_bounds__(256) void gemm_mfma(
    const void* __restrict__ Aany, const u16* __restrict__ Alo_,
    const u16* __restrict__ Bhi_, const u16* __restrict__ Blo_,
    float* __restrict__ Cf, u16* __restrict__ Chi, u16* __restrict__ Clo,
    const float* __restrict__ bias, int N, int Kd, int gx)
{
    constexpr int SA = AF32 ? 48 : 32;
    __shared__ u16 sAh[128 * SA];
    __shared__ u16 sAl[SPLIT ? 128 * SA : 8];
    __shared__ u16 sBh[128 * 32];
    __shared__ u16 sBl[SPLIT ? 128 * 32 : 8];

    const int swz = xcd_swz(blockIdx.x, gridDim.x);
    const int nst_x = gx >> 2;
    const int st = swz >> 4, off = swz & 15;
    const int bxi = (st % nst_x) * 4 + (off & 3);
    const int byi = (st / nst_x) * 4 + (off >> 2);

    const int t = threadIdx.x;
    const int w = t >> 6;
    const int l = t & 63;
    const long brow = (long)byi * 128;
    const long bcol = (long)bxi * 128;

    const int grow = l >> 2;
    const int gcol = ((l & 3) ^ ((l >> 3) & 3)) * 8;

    const int wr = (w >> 1) * 64;
    const int wc = (w & 1) * 64;
    const int fr = l & 15;
    const int kg = l >> 4;
    const int kq = (kg ^ ((fr >> 1) & 3)) * 8;

    f4 acc[4][4];
#pragma unroll
    for (int m = 0; m < 4; m++)
#pragma unroll
        for (int n = 0; n < 4; n++) acc[m][n] = (f4){0.f, 0.f, 0.f, 0.f};

    const int nkt = Kd >> 5;
    for (int kt = 0; kt < nkt; ++kt) {
        const int k0 = kt * 32;

#pragma unroll
        for (int i = 0; i < 2; ++i) {
            const long r = bcol + i * 64 + w * 16 + grow;
            const int lb = i * 2048 + w * 512;
            gl16(Bhi_ + r * Kd + k0 + gcol, sBh + lb);
            if constexpr (SPLIT) gl16(Blo_ + r * Kd + k0 + gcol, sBl + lb);
        }

        if constexpr (!AF32) {
            const u16* Ahi = (const u16*)Aany;
#pragma unroll
            for (int i = 0; i < 2; ++i) {
                const long r = brow + i * 64 + w * 16 + grow;
                const int lb = i * 2048 + w * 512;
                gl16(Ahi + r * Kd + k0 + gcol, sAh + lb);
                if constexpr (SPLIT) gl16(Alo_ + r * Kd + k0 + gcol, sAl + lb);
            }
        } else {
            const float* Af = (const float*)Aany;
            const int ar = w * 8 + (l >> 3);
            const int cF = (l & 7) * 4;
#pragma unroll
            for (int j = 0; j < 4; ++j) {
                const int r = j * 32 + ar;
                const f4 v = *(const f4*)(Af + (brow + r) * (long)Kd + k0 + cF);
                u16 h[4], lw[4];
#pragma unroll
                for (int qq = 0; qq < 4; ++qq) {
                    h[qq] = f2bf(v[qq]);
                    if constexpr (SPLIT) lw[qq] = f2bf(v[qq] - bf2f(h[qq]));
                }
                *(bf4*)&sAh[r * SA + cF] = *(bf4*)h;
                if constexpr (SPLIT) *(bf4*)&sAl[r * SA + cF] = *(bf4*)lw;
            }
        }
        __syncthreads();

        bf8 fah[4], fbh[4], fal[4], fbl[4];
#pragma unroll
        for (int m = 0; m < 4; ++m) {
            if constexpr (AF32) {
                fah[m] = *(bf8*)&sAh[(wr + m * 16 + fr) * SA + kg * 8];
                if constexpr (SPLIT) fal[m] = *(bf8*)&sAl[(wr + m * 16 + fr) * SA + kg * 8];
            } else {
                fah[m] = *(bf8*)&sAh[(wr + m * 16 + fr) * 32 + kq];
                if constexpr (SPLIT) fal[m] = *(bf8*)&sAl[(wr + m * 16 + fr) * 32 + kq];
            }
            fbh[m] = *(bf8*)&sBh[(wc + m * 16 + fr) * 32 + kq];
            if constexpr (SPLIT) fbl[m] = *(bf8*)&sBl[(wc + m * 16 + fr) * 32 + kq];
        }
#pragma unroll
        for (int m = 0; m < 4; ++m)
#pragma unroll
            for (int n = 0; n < 4; ++n) {
                acc[m][n] = __builtin_amdgcn_mfma_f32_16x16x32_bf16(fah[m], fbh[n], acc[m][n], 0, 0, 0);
                if constexpr (SPLIT) {
                    acc[m][n] = __builtin_amdgcn_mfma_f32_16x16x32_bf16(fah[m], fbl[n], acc[m][n], 0, 0, 0);
                    acc[m][n] = __builtin_amdgcn_mfma_f32_16x16x32_bf16(fal[m], fbh[n], acc[m][n], 0, 0, 0);
                }
            }
        __syncthreads();
    }

#pragma unroll
    for (int n = 0; n < 4; ++n) {
        const long c = bcol + wc + n * 16 + fr;
        float bv = 0.f;
        if constexpr (EPIS) bv = bias[c];
#pragma unroll
        for (int m = 0; m < 4; ++m) {
            const long r0 = brow + wr + m * 16 + kg * 4;
#pragma unroll
            for (int r = 0; r < 4; ++r) {
                const float v = acc[m][n][r] + bv;
                if constexpr (EPIS) {
                    const u16 h = f2bf(v);
                    Chi[(r0 + r) * (long)N + c] = h;
                    Clo[(r0 + r) * (long)N + c] = f2bf(v - bf2f(h));
                } else {
                    Cf[(r0 + r) * (long)N + c] = v;
                }
            }
        }
    }
}

// ---------------------------------------------------------------------------
// Column softmax finish (partials from gemm8s epilogue: pm/ps[16][N_Kn])
// ---------------------------------------------------------------------------
#define RCHUNK 128

__global__ __launch_bounds__(256) void softmax_combine(
    const float* __restrict__ pm, const float* __restrict__ ps,
    float* __restrict__ fm, float* __restrict__ fsinv)
{
    const int col = blockIdx.x * 256 + threadIdx.x;
    float m = -3.4e38f;
#pragma unroll
    for (int i = 0; i < 16; i++) m = fmaxf(m, pm[(size_t)i * N_Kn + col]);
    float s = 0.f;
#pragma unroll
    for (int i = 0; i < 16; i++)
        s += ps[(size_t)i * N_Kn + col] * __expf(pm[(size_t)i * N_Kn + col] - m);
    fm[col] = m;
    fsinv[col] = 1.f / s;
}

__global__ __launch_bounds__(256) void softmax_norm(
    float* __restrict__ align, u16* __restrict__ abf,
    const float* __restrict__ fm, const float* __restrict__ fsinv)
{
    const int col = blockIdx.x * 256 + threadIdx.x;
    const int r0 = blockIdx.y * RCHUNK;
    const float m = fm[col], si = fsinv[col];
    for (int r = 0; r < RCHUNK; r++) {
        const size_t idx = (size_t)(r0 + r) * N_Kn + col;
        const float v = __expf(align[idx] - m) * si;
        align[idx] = v;
        abf[idx] = f2bf(v);
    }
}

// ---------------------------------------------------------------------------
extern "C" void kernel_launch(void* const* d_in, const int* in_sizes, int n_in,
                              void* d_out, int out_size, void* d_ws, size_t ws_size,
                              hipStream_t stream)
{
    const float* sentences = (const float*)d_in[0];  // [4096][1024]
    const float* knowledge = (const float*)d_in[1];  // [8192][3072]
    const float* Ws = (const float*)d_in[2];         // [1024][1024]
    const float* bs = (const float*)d_in[3];         // [1024]
    const float* Wk = (const float*)d_in[4];         // [3072][1024]
    const float* bk = (const float*)d_in[5];         // [1024]

    float* out_fused = (float*)d_out;                        // [4096][3072]
    float* out_attn = (float*)d_out + (size_t)N_S * K3;      // [4096][8192]

    // workspace (~114 MB); first 64 MB reused as attn_bf16 after GEMM4
    char* w = (char*)d_ws;
    u16* attn_bf = (u16*)w;
    u16* WsT_hi = (u16*)w; w += (size_t)HID * SENT * 2;
    u16* WsT_lo = (u16*)w; w += (size_t)HID * SENT * 2;
    u16* WkT_hi = (u16*)w; w += (size_t)HID * K3 * 2;
    u16* WkT_lo = (u16*)w; w += (size_t)HID * K3 * 2;
    u16* S_hi   = (u16*)w; w += (size_t)N_S * HID * 2;
    u16* S_lo   = (u16*)w; w += (size_t)N_S * HID * 2;
    u16* K_hi   = (u16*)w; w += (size_t)N_Kn * HID * 2;
    u16* K_lo   = (u16*)w; w += (size_t)N_Kn * HID * 2;      // end = 64 MB
    u16* kT     = (u16*)w; w += (size_t)K3 * N_Kn * 2;
    float* pm   = (float*)w; w += (size_t)16 * N_Kn * 4;
    float* ps   = (float*)w; w += (size_t)16 * N_Kn * 4;
    float* fm   = (float*)w; w += (size_t)N_Kn * 4;
    float* fsv  = (float*)w; w += (size_t)N_Kn * 4;

    // 1. weight transposes (split) + knowledge^T (bf16)
    transpose_split_f32<<<dim3(HID / 32, SENT / 32), 256, 0, stream>>>(Ws, WsT_hi, WsT_lo, SENT, HID);
    transpose_split_f32<<<dim3(HID / 32, K3 / 32), 256, 0, stream>>>(Wk, WkT_hi, WkT_lo, K3, HID);
    transpose_f32_bf16<<<dim3(K3 / 32, N_Kn / 32), 256, 0, stream>>>(knowledge, kT, N_Kn, K3);

    // 2. S = sentences @ Ws + bs -> split bf16
    gemm_mfma<true, true, true><<<(HID / 128) * (N_S / 128), 256, 0, stream>>>(
        sentences, nullptr, WsT_hi, WsT_lo, nullptr, S_hi, S_lo, bs, HID, SENT, HID / 128);

    // 3. K = knowledge @ Wk + bk -> split bf16 (pipelined, reg-staged A)
    gemm8f<<<256, 512, 0, stream>>>(
        knowledge, WkT_hi, WkT_lo, K_hi, K_lo, bk, HID, K3);

    // 4. align = S @ K^T -> f32 into attentions slot; epilogue emits partials
    gemm8s<<<(N_Kn / 128) * (N_S / 256), 512, 0, stream>>>(
        S_hi, S_lo, K_hi, K_lo, out_attn, pm, ps, N_Kn, HID);

    // 5. column softmax finish (axis 0), in place; emit bf16 attn
    softmax_combine<<<dim3(N_Kn / 256), 256, 0, stream>>>(pm, ps, fm, fsv);
    softmax_norm<<<dim3(N_Kn / 256, N_S / RCHUNK), 256, 0, stream>>>(out_attn, attn_bf, fm, fsv);

    // 6. fused = attn_bf16 @ kT -> f32
    gemm8b<<<(K3 / 192) * (N_S / 256), 512, 0, stream>>>(
        attn_bf, kT, out_fused, K3, N_Kn, K3 / 192);
}

// Round 17
// 675.191 us; speedup vs baseline: 1.1954x; 1.0064x over previous
//
#include <hip/hip_runtime.h>
#include <hip/hip_bf16.h>
#include <cstdint>
#include <cstddef>

#define N_S 4096
#define N_Kn 8192
#define HID 1024
#define SENT 1024
#define K3 3072

typedef __attribute__((ext_vector_type(4))) float f4;
typedef __attribute__((ext_vector_type(8))) short bf8;
typedef __attribute__((ext_vector_type(4))) short bf4;
typedef unsigned short u16;

__device__ __forceinline__ u16 f2bf(float x) {
    __hip_bfloat16 h = __float2bfloat16(x);   // HW RNE
    return __builtin_bit_cast(u16, h);
}
__device__ __forceinline__ float bf2f(u16 u) {
    union { unsigned int u; float f; } v; v.u = ((unsigned int)u) << 16;
    return v.f;
}

// async global->LDS, 16 bytes per lane; LDS dest = wave-uniform base + lane*16
__device__ __forceinline__ void gl16(const u16* g, u16* l) {
    __builtin_amdgcn_global_load_lds(
        (const __attribute__((address_space(1))) void*)g,
        (__attribute__((address_space(3))) void*)l, 16, 0, 0);
}

// bijective XCD swizzle (nwg % 8 == 0)
__device__ __forceinline__ int xcd_swz(int bid, int nwg) {
    const int cpx = nwg >> 3;
    return (bid & 7) * cpx + (bid >> 3);
}

#define BARR __builtin_amdgcn_s_barrier()
#define PRIO1 __builtin_amdgcn_s_setprio(1)
#define PRIO0 __builtin_amdgcn_s_setprio(0)
#define VM8  asm volatile("s_waitcnt vmcnt(8)" ::: "memory")
#define VM7  asm volatile("s_waitcnt vmcnt(7)" ::: "memory")
#define VM6  asm volatile("s_waitcnt vmcnt(6)" ::: "memory")
#define VM2  asm volatile("s_waitcnt vmcnt(2)" ::: "memory")
#define VM0  asm volatile("s_waitcnt vmcnt(0)" ::: "memory")
#define LGKM0 asm volatile("s_waitcnt lgkmcnt(0)" ::: "memory")

// ---------------------------------------------------------------------------
// Transposes
// ---------------------------------------------------------------------------
__global__ __launch_bounds__(256) void transpose_split_f32(
    const float* __restrict__ in, u16* __restrict__ hi, u16* __restrict__ lo,
    int R, int C)
{
    __shared__ float tile[32][33];
    const int bx = blockIdx.x * 32, by = blockIdx.y * 32;
    const int tx = threadIdx.x & 31, ty = threadIdx.x >> 5;
#pragma unroll
    for (int i = 0; i < 32; i += 8)
        tile[ty + i][tx] = in[(size_t)(by + ty + i) * C + bx + tx];
    __syncthreads();
#pragma unroll
    for (int i = 0; i < 32; i += 8) {
        const float v = tile[tx][ty + i];
        const u16 h = f2bf(v);
        const size_t o = (size_t)(bx + ty + i) * R + by + tx;
        hi[o] = h;
        lo[o] = f2bf(v - bf2f(h));
    }
}

__global__ __launch_bounds__(256) void transpose_f32_bf16(
    const float* __restrict__ in, u16* __restrict__ out, int R, int C)
{
    __shared__ float tile[32][33];
    const int bx = blockIdx.x * 32, by = blockIdx.y * 32;
    const int tx = threadIdx.x & 31, ty = threadIdx.x >> 5;
#pragma unroll
    for (int i = 0; i < 32; i += 8)
        tile[ty + i][tx] = in[(size_t)(by + ty + i) * C + bx + tx];
    __syncthreads();
#pragma unroll
    for (int i = 0; i < 32; i += 8)
        out[(size_t)(bx + ty + i) * R + by + tx] = f2bf(tile[tx][ty + i]);
}

// ---------------------------------------------------------------------------
// gemm8b: plain bf16 C = A @ B^T (GEMM6). BM=256, BN=192, BK=64, 512 thr
// (8 waves 4Mx2N), single-barrier 3-phase schedule, counted vmcnt(7),
// chunk-XOR swizzle, hoisted staging pointers. LDS 112 KiB.
//   phA: read fa0(4)+fb1(6); BARR; MMA Q(0,0)+Q(0,1)  [24 MFMA]
//   phB: read fa1(4); stage t+2 B; BARR; MMA Q(1,0)   [12]
//   phC: stage t+2 A; VM7; BARR; read next fb0(6); MMA Q(1,1) [12]
// Hazards: each stage is one barrier after the reads of its region
// (fb0/fb1 retired at BARR-A -> stB3 in phB; fa1 retired at BARR-B ->
// stA4 in phC) — identical discipline to the verified round-9 kernel.
// ---------------------------------------------------------------------------
#define GB_LDA(buf, mh) \
  _Pragma("unroll") for (int mf_ = 0; mf_ < 2; ++mf_) \
  _Pragma("unroll") for (int kk_ = 0; kk_ < 2; ++kk_) \
    fa[mf_][kk_] = *(const bf8*)&sA[buf][(wm*64 + ((mh)*2+mf_)*16 + fr)*64 + (((kk_*4+kg) ^ (fr&7))<<3)];

#define GB_LDB(buf, nh, FB) \
  _Pragma("unroll") for (int nf_ = 0; nf_ < 3; ++nf_) \
  _Pragma("unroll") for (int kk_ = 0; kk_ < 2; ++kk_) \
    FB[nf_][kk_] = *(const bf8*)&sB[buf][(wn*96 + ((nh)*3+nf_)*16 + fr)*64 + (((kk_*4+kg) ^ (fr&7))<<3)];

#define GB_MMA(mh, nh, FB) \
  _Pragma("unroll") for (int kk_ = 0; kk_ < 2; ++kk_) \
  _Pragma("unroll") for (int mf_ = 0; mf_ < 2; ++mf_) \
  _Pragma("unroll") for (int nf_ = 0; nf_ < 3; ++nf_) \
    acc[(mh)*2+mf_][(nh)*3+nf_] = __builtin_amdgcn_mfma_f32_16x16x32_bf16( \
        fa[mf_][kk_], FB[nf_][kk_], acc[(mh)*2+mf_][(nh)*3+nf_], 0, 0, 0);

__global__ __launch_bounds__(512, 2) void gemm8b(
    const u16* __restrict__ A, const u16* __restrict__ B,
    float* __restrict__ C, int N, int Kd, int gx)
{
    __shared__ u16 sA[2][256 * 64];
    __shared__ u16 sB[2][192 * 64];

    const int swz = xcd_swz(blockIdx.x, gridDim.x);
    const int bx = swz % gx, by = swz / gx;
    const long brow = (long)by * 256, bcol = (long)bx * 192;

    const int t = threadIdx.x;
    const int w = t >> 6, l = t & 63;
    const int fr = l & 15, kg = l >> 4;
    const int wm = w >> 1;
    const int wn = w & 1;

    const int srow = t >> 3;
    const int schk = ((t & 7) ^ (srow & 7)) << 3;
    const int sldb = w << 9;

    const u16* pA0 = A + (brow +   0 + srow) * (long)Kd + schk;
    const u16* pA1 = A + (brow +  64 + srow) * (long)Kd + schk;
    const u16* pA2 = A + (brow + 128 + srow) * (long)Kd + schk;
    const u16* pA3 = A + (brow + 192 + srow) * (long)Kd + schk;
    const u16* pB0 = B + (bcol +   0 + srow) * (long)Kd + schk;
    const u16* pB1 = B + (bcol +  64 + srow) * (long)Kd + schk;
    const u16* pB2 = B + (bcol + 128 + srow) * (long)Kd + schk;

    auto stB3 = [&](int buf) {
        u16* base = &sB[buf][0];
        gl16(pB0, base + sldb);
        gl16(pB1, base + 4096 + sldb);
        gl16(pB2, base + 8192 + sldb);
    };
    auto stA4 = [&](int buf) {
        u16* base = &sA[buf][0];
        gl16(pA0, base + sldb);
        gl16(pA1, base + 4096 + sldb);
        gl16(pA2, base + 8192 + sldb);
        gl16(pA3, base + 12288 + sldb);
    };
    auto advance = [&]() {
        pA0 += 64; pA1 += 64; pA2 += 64; pA3 += 64;
        pB0 += 64; pB1 += 64; pB2 += 64;
    };

    f4 acc[4][6];
#pragma unroll
    for (int m = 0; m < 4; ++m)
#pragma unroll
        for (int n = 0; n < 6; ++n) acc[m][n] = (f4){0.f, 0.f, 0.f, 0.f};

    bf8 fa[2][2], fb0[3][2], fb1[3][2];

    const int NK = Kd >> 6;

    stB3(0); stA4(0); advance();
    stB3(1); stA4(1); advance();
    VM7;
    BARR;
    GB_LDB(0, 0, fb0);

    for (int kt = 0; kt < NK; ++kt) {
        const int buf = kt & 1;
        const bool s2 = kt + 2 < NK;
        const bool more = kt + 1 < NK;

        // phA: fa0 + fb1 reads; barrier; MMA Q(0,0) + Q(0,1)
        GB_LDA(buf, 0);
        GB_LDB(buf, 1, fb1);
        BARR; PRIO1; GB_MMA(0, 0, fb0); GB_MMA(0, 1, fb1); PRIO0;

        // phB: fa1 reads + stage t+2 B (fb reads retired at BARR-A); MMA Q(1,0)
        GB_LDA(buf, 1);
        if (s2) { stB3(buf); }
        BARR; PRIO1; GB_MMA(1, 0, fb0); PRIO0;

        // phC: stage t+2 A (fa1 retired at BARR-B); counted wait; barrier;
        // prefetch next tile's fb0 from buf^1; MMA Q(1,1)
        if (s2) { stA4(buf); VM7; } else { VM0; }
        BARR;
        if (more) { GB_LDB(buf ^ 1, 0, fb0); }
        PRIO1; GB_MMA(1, 1, fb1); PRIO0;
        advance();
    }

#pragma unroll
    for (int n = 0; n < 6; ++n) {
        const long c = bcol + wn * 96 + n * 16 + fr;
#pragma unroll
        for (int m = 0; m < 4; ++m) {
            const long r0 = brow + wm * 64 + m * 16 + kg * 4;
#pragma unroll
            for (int r = 0; r < 4; ++r)
                C[(r0 + r) * (long)N + c] = acc[m][n][r];
        }
    }
}

// ---------------------------------------------------------------------------
// Shared split-GEMM phase macros (gemm8s / gemm8f)
// ---------------------------------------------------------------------------
#define GS_LD(buf) \
  _Pragma("unroll") for (int m_ = 0; m_ < 4; ++m_) { \
    fah[m_] = *(const bf8*)&sAh[buf][(wm*64 + m_*16 + fr)*32 + kq]; \
    fal[m_] = *(const bf8*)&sAl[buf][(wm*64 + m_*16 + fr)*32 + kq]; } \
  _Pragma("unroll") for (int j_ = 0; j_ < 4; ++j_) { \
    fbh[j_] = *(const bf8*)&sBh[buf][(wn*64 + j_*16 + fr)*32 + kq]; \
    fbl[j_] = *(const bf8*)&sBl[buf][(wn*64 + j_*16 + fr)*32 + kq]; }

#define GS_MMA(nlo) \
  _Pragma("unroll") for (int m_ = 0; m_ < 4; ++m_) \
  _Pragma("unroll") for (int j_ = 0; j_ < 2; ++j_) { \
    const int n_ = (nlo)*2 + j_; \
    acc[m_][n_] = __builtin_amdgcn_mfma_f32_16x16x32_bf16(fah[m_], fbh[n_], acc[m_][n_], 0, 0, 0); \
    acc[m_][n_] = __builtin_amdgcn_mfma_f32_16x16x32_bf16(fah[m_], fbl[n_], acc[m_][n_], 0, 0, 0); \
    acc[m_][n_] = __builtin_amdgcn_mfma_f32_16x16x32_bf16(fal[m_], fbh[n_], acc[m_][n_], 0, 0, 0); }

// ---------------------------------------------------------------------------
// gemm8s: split-bf16 C = A @ B^T (GEMM4), A,B pre-split hi/lo in workspace.
// BM=256, BN=128, BK=32, 512 thr (8 waves 4Mx2N). Epilogue emits per-column
// partial max & exp-sum over the block's 256 rows -> pm/ps[16][N].
// ---------------------------------------------------------------------------
__global__ __launch_bounds__(512, 2) void gemm8s(
    const u16* __restrict__ Ah, const u16* __restrict__ Al,
    const u16* __restrict__ Bh, const u16* __restrict__ Bl,
    float* __restrict__ C, float* __restrict__ pm, float* __restrict__ ps,
    int N, int Kd)
{
    __shared__ u16 sAh[2][8192], sAl[2][8192];
    __shared__ u16 sBh[2][4096], sBl[2][4096];

    const int bid = blockIdx.x;
    const int q = bid >> 3;
    const int by = (bid & 7) * 2 + (q & 1);   // 0..15
    const int bx = q >> 1;                    // 0..63
    const long brow = (long)by * 256, bcol = (long)bx * 128;

    const int t = threadIdx.x;
    const int w = t >> 6, l = t & 63;
    const int fr = l & 15, kg = l >> 4;
    const int wm = w >> 1;
    const int wn = w & 1;
    const int kq = (kg ^ ((fr >> 1) & 3)) << 3;

    const int srow = t >> 2;
    const int schk = ((t & 3) ^ ((t >> 3) & 3)) << 3;
    const int sldb = w << 9;

    const u16* pAh0 = Ah + (brow + srow) * (long)Kd + schk;
    const u16* pAh1 = Ah + (brow + 128 + srow) * (long)Kd + schk;
    const u16* pAl0 = Al + (brow + srow) * (long)Kd + schk;
    const u16* pAl1 = Al + (brow + 128 + srow) * (long)Kd + schk;
    const u16* pBh0 = Bh + (bcol + srow) * (long)Kd + schk;
    const u16* pBl0 = Bl + (bcol + srow) * (long)Kd + schk;

    auto stage6 = [&](int buf) {
        gl16(pBh0, &sBh[buf][sldb]);
        gl16(pBl0, &sBl[buf][sldb]);
        gl16(pAh0, &sAh[buf][sldb]);
        gl16(pAh1, &sAh[buf][4096 + sldb]);
        gl16(pAl0, &sAl[buf][sldb]);
        gl16(pAl1, &sAl[buf][4096 + sldb]);
    };
    auto advance = [&]() {
        pAh0 += 32; pAh1 += 32; pAl0 += 32; pAl1 += 32;
        pBh0 += 32; pBl0 += 32;
    };

    f4 acc[4][4];
#pragma unroll
    for (int m = 0; m < 4; ++m)
#pragma unroll
        for (int n = 0; n < 4; ++n) acc[m][n] = (f4){0.f, 0.f, 0.f, 0.f};

    bf8 fah[4], fal[4], fbh[4], fbl[4];

    const int NK = Kd >> 5;

    stage6(0); advance();
    stage6(1); advance();
    VM6;
    BARR;

    for (int kt = 0; kt < NK; ++kt) {
        const int buf = kt & 1;
        const bool s2 = kt + 2 < NK;

        GS_LD(buf);
        BARR; PRIO1; GS_MMA(0); PRIO0;

        if (s2) { stage6(buf); VM6; } else { VM0; }
        BARR;
        PRIO1; GS_MMA(1); PRIO0;
        advance();
    }

    // ---- epilogue 1: C write ----
#pragma unroll
    for (int n = 0; n < 4; ++n) {
        const long c = bcol + wn * 64 + n * 16 + fr;
#pragma unroll
        for (int m = 0; m < 4; ++m) {
            const long r0 = brow + wm * 64 + m * 16 + kg * 4;
#pragma unroll
            for (int r = 0; r < 4; ++r)
                C[(r0 + r) * (long)N + c] = acc[m][n][r];
        }
    }

    // ---- epilogue 2: per-column partial max & exp-sum over 256 rows ----
    float* red = (float*)&sAh[0][0];
    float lmax[4];
#pragma unroll
    for (int n = 0; n < 4; ++n) {
        float m = -3.4e38f;
#pragma unroll
        for (int mm = 0; mm < 4; ++mm)
#pragma unroll
            for (int r = 0; r < 4; ++r) m = fmaxf(m, acc[mm][n][r]);
        m = fmaxf(m, __shfl_xor(m, 16, 64));
        m = fmaxf(m, __shfl_xor(m, 32, 64));
        lmax[n] = m;
    }
    BARR;
    if (kg == 0) {
#pragma unroll
        for (int n = 0; n < 4; ++n)
            red[wm * 128 + wn * 64 + n * 16 + fr] = lmax[n];
    }
    BARR;
    float bmax[4];
#pragma unroll
    for (int n = 0; n < 4; ++n) {
        const int c = wn * 64 + n * 16 + fr;
        bmax[n] = fmaxf(fmaxf(red[c], red[128 + c]),
                        fmaxf(red[256 + c], red[384 + c]));
    }
    BARR;
    float lsum[4];
#pragma unroll
    for (int n = 0; n < 4; ++n) {
        float s = 0.f;
#pragma unroll
        for (int mm = 0; mm < 4; ++mm)
#pragma unroll
            for (int r = 0; r < 4; ++r) s += __expf(acc[mm][n][r] - bmax[n]);
        s += __shfl_xor(s, 16, 64);
        s += __shfl_xor(s, 32, 64);
        lsum[n] = s;
    }
    if (kg == 0) {
#pragma unroll
        for (int n = 0; n < 4; ++n)
            red[wm * 128 + wn * 64 + n * 16 + fr] = lsum[n];
    }
    BARR;
    if (wm == 0 && kg == 0) {
#pragma unroll
        for (int n = 0; n < 4; ++n) {
            const int c = wn * 64 + n * 16 + fr;
            const float bs = red[c] + red[128 + c] + red[256 + c] + red[384 + c];
            pm[(size_t)by * N + bcol + c] = bmax[n];
            ps[(size_t)by * N + bcol + c] = bs;
        }
    }
}

// ---------------------------------------------------------------------------
// gemm8f: split-bf16 C = A @ B^T for f32 A (GEMM2 & GEMM3).
// Same schedule as gemm8s; A reg-staged (issue-early/write-late, vmcnt(2)).
// Grid map: q=bid>>3; by=((bid&7)<<lsh)|(q&((1<<lsh)-1)); bx=q>>lsh.
// Epilogue: + bias, split hi/lo store.
// ---------------------------------------------------------------------------
__global__ __launch_bounds__(512, 2) void gemm8f(
    const float* __restrict__ Af, const u16* __restrict__ Bh, const u16* __restrict__ Bl,
    u16* __restrict__ Chi, u16* __restrict__ Clo, const float* __restrict__ bias,
    int N, int Kd, int lsh)
{
    __shared__ u16 sAh[2][8192], sAl[2][8192];
    __shared__ u16 sBh[2][4096], sBl[2][4096];

    const int bid = blockIdx.x;
    const int q = bid >> 3;
    const int by = ((bid & 7) << lsh) | (q & ((1 << lsh) - 1));
    const int bx = q >> lsh;
    const long brow = (long)by * 256, bcol = (long)bx * 128;

    const int t = threadIdx.x;
    const int w = t >> 6, l = t & 63;
    const int fr = l & 15, kg = l >> 4;
    const int wm = w >> 1;
    const int wn = w & 1;
    const int kq = (kg ^ ((fr >> 1) & 3)) << 3;

    const int srow = t >> 2;
    const int schk = ((t & 3) ^ ((t >> 3) & 3)) << 3;
    const int sldb = w << 9;
    const u16* pBh0 = Bh + (bcol + srow) * (long)Kd + schk;
    const u16* pBl0 = Bl + (bcol + srow) * (long)Kd + schk;

    const float* pA0 = Af + (brow + srow) * (long)Kd + (t & 3) * 8;
    const float* pA1 = Af + (brow + 128 + srow) * (long)Kd + (t & 3) * 8;
    const int adst = srow * 32 + schk;

    auto cvt_write = [&](int buf, int dst, const f4& x0, const f4& x1) {
        float xv[8];
        *(f4*)&xv[0] = x0; *(f4*)&xv[4] = x1;
        u16 h[8], lw[8];
#pragma unroll
        for (int j = 0; j < 8; ++j) {
            h[j] = f2bf(xv[j]);
            lw[j] = f2bf(xv[j] - bf2f(h[j]));
        }
        *(bf8*)&sAh[buf][dst] = *(bf8*)h;
        *(bf8*)&sAl[buf][dst] = *(bf8*)lw;
    };

    f4 acc[4][4];
#pragma unroll
    for (int m = 0; m < 4; ++m)
#pragma unroll
        for (int n = 0; n < 4; ++n) acc[m][n] = (f4){0.f, 0.f, 0.f, 0.f};

    bf8 fah[4], fal[4], fbh[4], fbl[4];

    const int NK = Kd >> 5;

    {
        f4 a00 = *(const f4*)(pA0);      f4 a01 = *(const f4*)(pA0 + 4);
        f4 a10 = *(const f4*)(pA1);      f4 a11 = *(const f4*)(pA1 + 4);
        gl16(pBh0, &sBh[0][sldb]); gl16(pBl0, &sBl[0][sldb]);
        f4 b00 = *(const f4*)(pA0 + 32); f4 b01 = *(const f4*)(pA0 + 36);
        f4 b10 = *(const f4*)(pA1 + 32); f4 b11 = *(const f4*)(pA1 + 36);
        gl16(pBh0 + 32, &sBh[1][sldb]); gl16(pBl0 + 32, &sBl[1][sldb]);
        VM8;
        cvt_write(0, adst, a00, a01);
        cvt_write(0, adst + 4096, a10, a11);
        VM2;
        cvt_write(1, adst, b00, b01);
        cvt_write(1, adst + 4096, b10, b11);
        LGKM0;
        BARR;
        pA0 += 64; pA1 += 64; pBh0 += 64; pBl0 += 64;
    }

    for (int kt = 0; kt < NK; ++kt) {
        const int buf = kt & 1;
        const bool s2 = kt + 2 < NK;

        GS_LD(buf);
        f4 x0, x1, y0, y1;
        if (s2) {
            x0 = *(const f4*)(pA0); x1 = *(const f4*)(pA0 + 4);
            y0 = *(const f4*)(pA1); y1 = *(const f4*)(pA1 + 4);
        }
        BARR; PRIO1; GS_MMA(0); PRIO0;

        if (s2) {
            gl16(pBh0, &sBh[buf][sldb]);
            gl16(pBl0, &sBl[buf][sldb]);
            VM2;
            cvt_write(buf, adst, x0, x1);
            cvt_write(buf, adst + 4096, y0, y1);
            LGKM0;
        } else {
            VM0;
        }
        BARR;
        PRIO1; GS_MMA(1); PRIO0;
        pA0 += 32; pA1 += 32; pBh0 += 32; pBl0 += 32;
    }

#pragma unroll
    for (int n = 0; n < 4; ++n) {
        const long c = bcol + wn * 64 + n * 16 + fr;
        const float bv = bias[c];
#pragma unroll
        for (int m = 0; m < 4; ++m) {
            const long r0 = brow + wm * 64 + m * 16 + kg * 4;
#pragma unroll
            for (int r = 0; r < 4; ++r) {
                const float v = acc[m][n][r] + bv;
                const u16 h = f2bf(v);
                Chi[(r0 + r) * (long)N + c] = h;
                Clo[(r0 + r) * (long)N + c] = f2bf(v - bf2f(h));
            }
        }
    }
}

// ---------------------------------------------------------------------------
// Column softmax finish (partials from gemm8s epilogue: pm/ps[16][N_Kn])
// ---------------------------------------------------------------------------
#define RCHUNK 128

__global__ __launch_bounds__(256) void softmax_combine(
    const float* __restrict__ pm, const float* __restrict__ ps,
    float* __restrict__ fm, float* __restrict__ fsinv)
{
    const int col = blockIdx.x * 256 + threadIdx.x;
    float m = -3.4e38f;
#pragma unroll
    for (int i = 0; i < 16; i++) m = fmaxf(m, pm[(size_t)i * N_Kn + col]);
    float s = 0.f;
#pragma unroll
    for (int i = 0; i < 16; i++)
        s += ps[(size_t)i * N_Kn + col] * __expf(pm[(size_t)i * N_Kn + col] - m);
    fm[col] = m;
    fsinv[col] = 1.f / s;
}

// 2 columns per thread: float2 loads/stores, packed u32 bf16 writes
__global__ __launch_bounds__(256) void softmax_norm(
    float* __restrict__ align, u16* __restrict__ abf,
    const float* __restrict__ fm, const float* __restrict__ fsinv)
{
    const int col = (blockIdx.x * 256 + threadIdx.x) * 2;
    const int r0 = blockIdx.y * RCHUNK;
    const float m0 = fm[col], m1 = fm[col + 1];
    const float s0 = fsinv[col], s1 = fsinv[col + 1];
    for (int r = 0; r < RCHUNK; r++) {
        const size_t idx = (size_t)(r0 + r) * N_Kn + col;
        const float2 x = *(const float2*)&align[idx];
        const float v0 = __expf(x.x - m0) * s0;
        const float v1 = __expf(x.y - m1) * s1;
        *(float2*)&align[idx] = make_float2(v0, v1);
        const unsigned int p = (unsigned int)f2bf(v0) | ((unsigned int)f2bf(v1) << 16);
        *(unsigned int*)&abf[idx] = p;
    }
}

// ---------------------------------------------------------------------------
extern "C" void kernel_launch(void* const* d_in, const int* in_sizes, int n_in,
                              void* d_out, int out_size, void* d_ws, size_t ws_size,
                              hipStream_t stream)
{
    const float* sentences = (const float*)d_in[0];  // [4096][1024]
    const float* knowledge = (const float*)d_in[1];  // [8192][3072]
    const float* Ws = (const float*)d_in[2];         // [1024][1024]
    const float* bs = (const float*)d_in[3];         // [1024]
    const float* Wk = (const float*)d_in[4];         // [3072][1024]
    const float* bk = (const float*)d_in[5];         // [1024]

    float* out_fused = (float*)d_out;                        // [4096][3072]
    float* out_attn = (float*)d_out + (size_t)N_S * K3;      // [4096][8192]

    // workspace (~114 MB); first 64 MB reused as attn_bf16 after GEMM4
    char* w = (char*)d_ws;
    u16* attn_bf = (u16*)w;
    u16* WsT_hi = (u16*)w; w += (size_t)HID * SENT * 2;
    u16* WsT_lo = (u16*)w; w += (size_t)HID * SENT * 2;
    u16* WkT_hi = (u16*)w; w += (size_t)HID * K3 * 2;
    u16* WkT_lo = (u16*)w; w += (size_t)HID * K3 * 2;
    u16* S_hi   = (u16*)w; w += (size_t)N_S * HID * 2;
    u16* S_lo   = (u16*)w; w += (size_t)N_S * HID * 2;
    u16* K_hi   = (u16*)w; w += (size_t)N_Kn * HID * 2;
    u16* K_lo   = (u16*)w; w += (size_t)N_Kn * HID * 2;      // end = 64 MB
    u16* kT     = (u16*)w; w += (size_t)K3 * N_Kn * 2;
    float* pm   = (float*)w; w += (size_t)16 * N_Kn * 4;
    float* ps   = (float*)w; w += (size_t)16 * N_Kn * 4;
    float* fm   = (float*)w; w += (size_t)N_Kn * 4;
    float* fsv  = (float*)w; w += (size_t)N_Kn * 4;

    // 1. weight transposes (split) + knowledge^T (bf16)
    transpose_split_f32<<<dim3(HID / 32, SENT / 32), 256, 0, stream>>>(Ws, WsT_hi, WsT_lo, SENT, HID);
    transpose_split_f32<<<dim3(HID / 32, K3 / 32), 256, 0, stream>>>(Wk, WkT_hi, WkT_lo, K3, HID);
    transpose_f32_bf16<<<dim3(K3 / 32, N_Kn / 32), 256, 0, stream>>>(knowledge, kT, N_Kn, K3);

    // 2. S = sentences @ Ws + bs -> split bf16 (pipelined, reg-staged A)
    gemm8f<<<128, 512, 0, stream>>>(
        sentences, WsT_hi, WsT_lo, S_hi, S_lo, bs, HID, SENT, 1);

    // 3. K = knowledge @ Wk + bk -> split bf16 (pipelined, reg-staged A)
    gemm8f<<<256, 512, 0, stream>>>(
        knowledge, WkT_hi, WkT_lo, K_hi, K_lo, bk, HID, K3, 2);

    // 4. align = S @ K^T -> f32 into attentions slot; epilogue emits partials
    gemm8s<<<(N_Kn / 128) * (N_S / 256), 512, 0, stream>>>(
        S_hi, S_lo, K_hi, K_lo, out_attn, pm, ps, N_Kn, HID);

    // 5. column softmax finish (axis 0), in place; emit bf16 attn
    softmax_combine<<<dim3(N_Kn / 256), 256, 0, stream>>>(pm, ps, fm, fsv);
    softmax_norm<<<dim3(N_Kn / 512, N_S / RCHUNK), 256, 0, stream>>>(out_attn, attn_bf, fm, fsv);

    // 6. fused = attn_bf16 @ kT -> f32 (3-phase single-barrier schedule)
    gemm8b<<<(K3 / 192) * (N_S / 256), 512, 0, stream>>>(
        attn_bf, kT, out_fused, K3, N_Kn, K3 / 192);
}